// Round 12
// baseline (372.128 us; speedup 1.0000x reference)
//
#include <hip/hip_runtime.h>
#include <hip/hip_bf16.h>
#include <math.h>

typedef __hip_bfloat16 bf16;
typedef __attribute__((ext_vector_type(4))) float f32x4;
typedef __attribute__((ext_vector_type(16))) float f32x16;
typedef __attribute__((ext_vector_type(8))) short s16x8;

__device__ __forceinline__ void async_cp16(void* lds, const void* g) {
    __builtin_amdgcn_global_load_lds((const __attribute__((address_space(1))) void*)g,
                                     (__attribute__((address_space(3))) void*)lds, 16, 0, 0);
}

// tanh-form GELU (max |diff| vs exact-erf gelu ~3e-3; threshold 0.154)
__device__ __forceinline__ float gelu_fast(float x) {
    float y = 1.5957691216f * (x + 0.044715f * x * x * x);
    float t = __expf(y);
    float th = 1.0f - 2.0f / (t + 1.0f);
    return 0.5f * x * (1.0f + th);
}

// ---------------------------------------------------------------------------
// fused f32 -> bf16 cast of all four weight matrices (one launch)
// ---------------------------------------------------------------------------
__global__ __launch_bounds__(256)
void cvt_all(const float* __restrict__ w0, const float* __restrict__ w1,
             const float* __restrict__ w2, const float* __restrict__ w3,
             bf16* __restrict__ o0, bf16* __restrict__ o1,
             bf16* __restrict__ o2, bf16* __restrict__ o3) {
    int i = blockIdx.x * 256 + threadIdx.x;
    const float* src; bf16* dst; int j = i;
    if (j < 786432)            { src = w0; dst = o0; }
    else if (j < 1048576)      { j -= 786432;  src = w1; dst = o1; }
    else if (j < 2097152)      { j -= 1048576; src = w2; dst = o2; }
    else                       { j -= 2097152; src = w3; dst = o3; }
    float4 v = ((const float4*)src)[j];
    union { bf16 o[4]; uint2 u; } pk;
    pk.o[0] = __float2bfloat16(v.x); pk.o[1] = __float2bfloat16(v.y);
    pk.o[2] = __float2bfloat16(v.z); pk.o[3] = __float2bfloat16(v.w);
    ((uint2*)dst)[j] = pk.u;
}

// ---------------------------------------------------------------------------
// LayerNorm (optionally x1 = x + pos first); writes fp32 residual + bf16 h
// ---------------------------------------------------------------------------
template <bool ADD>
__global__ __launch_bounds__(256)
void ln_kernel(const float* __restrict__ xin, const float* __restrict__ pos,
               const float* __restrict__ gam, const float* __restrict__ bet,
               float* __restrict__ x1, bf16* __restrict__ hout) {
    const int row = blockIdx.x, tid = threadIdx.x;
    const size_t off = (size_t)row * 1024;
    float4 v = ((const float4*)(xin + off))[tid];
    if constexpr (ADD) {
        float4 p = ((const float4*)(pos + off))[tid];
        v.x += p.x; v.y += p.y; v.z += p.z; v.w += p.w;
        ((float4*)(x1 + off))[tid] = v;
    }
    float s  = v.x + v.y + v.z + v.w;
    float s2 = v.x*v.x + v.y*v.y + v.z*v.z + v.w*v.w;
#pragma unroll
    for (int o = 32; o >= 1; o >>= 1) { s += __shfl_xor(s, o); s2 += __shfl_xor(s2, o); }
    __shared__ float sS[4], sS2[4];
    int w = tid >> 6, lane = tid & 63;
    if (lane == 0) { sS[w] = s; sS2[w] = s2; }
    __syncthreads();
    float mean = (sS[0] + sS[1] + sS[2] + sS[3]) * (1.f / 1024.f);
    float e2   = (sS2[0] + sS2[1] + sS2[2] + sS2[3]) * (1.f / 1024.f);
    float rstd = rsqrtf(e2 - mean * mean + 1e-5f);
    float4 gv = ((const float4*)gam)[tid], bv = ((const float4*)bet)[tid];
    bf16* ho = hout + off + tid * 4;
    ho[0] = __float2bfloat16((v.x - mean) * rstd * gv.x + bv.x);
    ho[1] = __float2bfloat16((v.y - mean) * rstd * gv.y + bv.y);
    ho[2] = __float2bfloat16((v.z - mean) * rstd * gv.z + bv.z);
    ho[3] = __float2bfloat16((v.w - mean) * rstd * gv.w + bv.w);
}

// ---------------------------------------------------------------------------
// GEMM 256x256 tile, BK=64 — R9 skeleton, R12: K-loop reverted to R9's
// EXACT form (separate As[2]/Bs[2] __shared__ arrays — R11's merged SM[4]
// coincided with the allocator dropping to 128 VGPR and spilling the
// 128-float accumulator; R9's layout verifiably allocated enough).
// 512 threads, 8 waves 2M x 4N, wave tile 128x64 (acc[8][4]), double-
// buffered counted-vmcnt depth-1:
//   compute(buf) ; s_barrier ; stage(t+2 -> buf) ; s_waitcnt vmcnt(8) ;
//   s_barrier
// LDS 2x64 = 128 KB -> 1 block/CU, 2 waves/SIMD. REQUIRES nk even.
// 1-D grid + bijective XCD chunk swizzle (nwg % 8 == 0); gx = N/256.
// MODE 1 = fused QKV epilogue: Qb (LoRA-q + 0.125*log2e), Kb, and Vt
// TRANSPOSED via a TWO-PASS 64 KB window in Bs (256 feat x 128 tok per
// pass; pass = wave's wm>>7). Swizzle ^(fl&7)<<3 -> 2-way max (free);
// coalesced 256B-per-halfwave Vt stores. Only 16 transient VGPRs (aA4).
// MODE 2: out = gelu(acc + bias)    (W1)
// ---------------------------------------------------------------------------
template <int MODE>
__global__ __launch_bounds__(512, 2)
void gemm_bk64(const bf16* __restrict__ A, const bf16* __restrict__ B,
               const float* __restrict__ bias, bf16* __restrict__ outp,
               const float* __restrict__ afterA, const float* __restrict__ loraB,
               bf16* __restrict__ Qb, bf16* __restrict__ Kb, bf16* __restrict__ Vt,
               int M, int N, int K, int gx) {
    __shared__ bf16 As[2][256 * 64];
    __shared__ bf16 Bs[2][256 * 64];
    const int tid = threadIdx.x;
    const int lane = tid & 63, w = tid >> 6;
    const int grp = lane >> 4, c16 = lane & 15;
    const int wm = (w & 1) * 128, wn = (w >> 1) * 64;   // 8 waves: 2M x 4N
    const int nwg = gridDim.x, bid = blockIdx.x;
    const int sw = (bid & 7) * (nwg >> 3) + (bid >> 3);   // XCD chunk swizzle
    const int bm = (sw / gx) * 256, bn = (sw % gx) * 256;

    f32x4 acc[8][4];
    const f32x4 zero = {0.f, 0.f, 0.f, 0.f};
#pragma unroll
    for (int mi = 0; mi < 8; mi++)
#pragma unroll
        for (int ni = 0; ni < 4; ni++) acc[mi][ni] = zero;

#define STAGE256(bufi, k0)                                                          \
    {                                                                               \
        const int buf_ = (bufi);                                                    \
        const int koff_ = (k0);                                                     \
        _Pragma("unroll") for (int t_ = 0; t_ < 4; t_++) {                          \
            int s_ = t_ * 512 + tid;                                                \
            int row_ = s_ >> 3, db_ = s_ & 7;                                       \
            int gb_ = (db_ ^ (row_ & 7)) << 3;                                      \
            async_cp16(&As[buf_][s_ * 8], A + (size_t)(bm + row_) * K + koff_ + gb_); \
            async_cp16(&Bs[buf_][s_ * 8], B + (size_t)(bn + row_) * K + koff_ + gb_); \
        }                                                                           \
    }

#define COMPUTE256(bufi)                                                            \
    {                                                                               \
        const int buf_ = (bufi);                                                    \
        _Pragma("unroll") for (int kc_ = 0; kc_ < 2; kc_++) {                       \
            s16x8 af_[8], bfv_[4];                                                  \
            _Pragma("unroll") for (int mi_ = 0; mi_ < 8; mi_++) {                   \
                int r_ = wm + mi_ * 16 + c16;                                       \
                af_[mi_] = *(const s16x8*)&As[buf_][r_ * 64 + ((((kc_ << 2) | grp) ^ (r_ & 7)) << 3)]; \
            }                                                                       \
            _Pragma("unroll") for (int ni_ = 0; ni_ < 4; ni_++) {                   \
                int r_ = wn + ni_ * 16 + c16;                                       \
                bfv_[ni_] = *(const s16x8*)&Bs[buf_][r_ * 64 + ((((kc_ << 2) | grp) ^ (r_ & 7)) << 3)]; \
            }                                                                       \
            _Pragma("unroll") for (int mi_ = 0; mi_ < 8; mi_++)                     \
                _Pragma("unroll") for (int ni_ = 0; ni_ < 4; ni_++)                 \
                    acc[mi_][ni_] = __builtin_amdgcn_mfma_f32_16x16x32_bf16(af_[mi_], bfv_[ni_], acc[mi_][ni_], 0, 0, 0); \
        }                                                                           \
    }

#define WAITV8 asm volatile("s_waitcnt vmcnt(8)" ::: "memory")
#define WAITV0 asm volatile("s_waitcnt vmcnt(0)" ::: "memory")

// One pipelined K-step. Invariant at entry: tile TQ complete in buf BQ;
// tile TQ+1 in flight (8 loads outstanding per thread).
#define STEP256(BQ, TQ)                                                             \
    {                                                                               \
        const int tq_ = (TQ);                                                       \
        COMPUTE256(BQ);                                                             \
        __builtin_amdgcn_s_barrier();        /* all waves done reading buf BQ */    \
        if (tq_ + 2 < nk) { STAGE256(BQ, (tq_ + 2) << 6); WAITV8; }                 \
        else { WAITV0; }                     /* tile TQ+1 now complete */           \
        __builtin_amdgcn_s_barrier();        /* everyone's TQ+1 loads landed */     \
    }

    const int nk = K >> 6;                   // K=1024 -> nk=16 (even)
    STAGE256(0, 0);
    STAGE256(1, 64);
    WAITV8;                                  // tile 0 complete
    __builtin_amdgcn_s_barrier();

    for (int t = 0; t < nk - 2; t += 2) {
        STEP256(0, t);
        STEP256(1, t + 1);
    }
    STEP256(0, nk - 2);                      // stages nothing; WAITV0
    COMPUTE256(1);                           // tile nk-1 in buf 1

#undef STEP256
#undef WAITV8
#undef WAITV0
#undef STAGE256
#undef COMPUTE256

    if constexpr (MODE == 1) {
        // fused QKV epilogue. role: 0=q, 1=k, 2=v (block-uniform).
        const int role = bn >> 10;
        const int g_b  = bm >> 11;           // batch index (rows 256-aligned)
        if (role == 2) {
            // v: bias + LoRA, transpose through Bs (64 KB window), 2 passes.
            // All waves crossed the barrier after their last Bs[0] read
            // (inside the final STEP), so writing Bs is safe without an
            // extra barrier before pass 0.
            char* tp = (char*)&Bs[0][0];     // 256 feat x 128 tok bf16, 256B rows
            const int tokb = bm & 2047;
#pragma unroll
            for (int pass = 0; pass < 2; pass++) {
                if ((wm >> 7) == pass) {     // this wave's tokens in this half
#pragma unroll
                    for (int mi = 0; mi < 8; mi++) {
                        float4 aA4[4];
#pragma unroll
                        for (int q = 0; q < 4; q++) {
                            int grow = bm + wm + mi * 16 + grp * 4 + q;
                            aA4[q] = ((const float4*)afterA)[(size_t)grow * 2 + 1];
                        }
#pragma unroll
                        for (int ni = 0; ni < 4; ni++) {
                            int fl = wn + ni * 16 + c16;      // feature 0..255
                            int cr = (bn & 1023) + fl;
                            float bv = bias[bn + fl];
                            float4 bw = ((const float4*)loraB)[1024 + cr];
                            union { bf16 e[4]; uint2 u; } pk;
#pragma unroll
                            for (int q = 0; q < 4; q++) {
                                float dv = (aA4[q].x*bw.x + aA4[q].y*bw.y + aA4[q].z*bw.z + aA4[q].w*bw.w) * 0.25f;
                                pk.e[q] = __float2bfloat16(acc[mi][ni][q] + bv + dv);
                            }
                            int tl = mi * 16 + grp * 4;       // 0..124 in half
                            int off = (fl * 256 + tl * 2) ^ ((fl & 7) << 3);
                            *(uint2*)(tp + off) = pk.u;
                        }
                    }
                }
                __syncthreads();
#pragma unroll
                for (int it = 0; it < 16; it++) {
                    int s = it * 512 + tid;
                    int fl = s >> 5, c4 = s & 31;             // 32 lanes = 1 feat
                    int off = (fl * 256 + c4 * 8) ^ ((fl & 7) << 3);
                    uint2 v = *(uint2*)(tp + off);
                    int cr = (bn & 1023) + fl;
                    int h = cr >> 6, d = cr & 63;
                    *(uint2*)&Vt[((size_t)(g_b * 16 + h) * 64 + d) * 2048 + tokb + pass * 128 + c4 * 4] = v;
                }
                if (pass == 0) __syncthreads();
            }
        } else if (role == 0) {
#pragma unroll
            for (int mi = 0; mi < 8; mi++) {
                float4 aA4[4];
#pragma unroll
                for (int q = 0; q < 4; q++) {
                    int grow = bm + wm + mi * 16 + grp * 4 + q;
                    aA4[q] = ((const float4*)afterA)[(size_t)grow * 2];
                }
#pragma unroll
                for (int ni = 0; ni < 4; ni++) {
                    int c  = bn + wn + ni * 16 + c16;
                    int cr = c & 1023;
                    int h  = cr >> 6, d = cr & 63;
                    float bv = bias[c];
                    float4 bw = ((const float4*)loraB)[cr];
#pragma unroll
                    for (int q = 0; q < 4; q++) {
                        int grow = bm + wm + mi * 16 + grp * 4 + q;
                        float dq = (aA4[q].x*bw.x + aA4[q].y*bw.y + aA4[q].z*bw.z + aA4[q].w*bw.w) * 0.25f;
                        float v = (acc[mi][ni][q] + bv + dq) * 0.18033688011f;  // 0.125*log2(e)
                        Qb[((size_t)(g_b * 16 + h) * 2048 + (grow & 2047)) * 64 + d] = __float2bfloat16(v);
                    }
                }
            }
        } else {
#pragma unroll
            for (int mi = 0; mi < 8; mi++)
#pragma unroll
                for (int ni = 0; ni < 4; ni++) {
                    int c  = bn + wn + ni * 16 + c16;
                    int cr = c & 1023;
                    int h  = cr >> 6, d = cr & 63;
                    float bv = bias[c];
#pragma unroll
                    for (int q = 0; q < 4; q++) {
                        int grow = bm + wm + mi * 16 + grp * 4 + q;
                        Kb[((size_t)(g_b * 16 + h) * 2048 + (grow & 2047)) * 64 + d] =
                            __float2bfloat16(acc[mi][ni][q] + bv);
                    }
                }
        }
    } else {
#pragma unroll
        for (int mi = 0; mi < 8; mi++)
#pragma unroll
            for (int ni = 0; ni < 4; ni++) {
                int r0 = bm + wm + mi * 16 + grp * 4;
                int c  = bn + wn + ni * 16 + c16;
                float bv = bias[c];
#pragma unroll
                for (int q = 0; q < 4; q++) {
                    size_t idx = (size_t)(r0 + q) * N + c;
                    float v = acc[mi][ni][q] + bv;
                    if constexpr (MODE == 2) v = gelu_fast(v);
                    outp[idx] = __float2bfloat16(v);
                }
            }
    }
}

// ---------------------------------------------------------------------------
// GEMM 128x64 tile, BK=64 — R7 config (proven): TRIPLE-BUFFERED counted-
// vmcnt pipeline. REQUIRES (K/64 - 1) % 3 == 0 (K=1024/4096 OK).
// Epilogue: out fp32 = acc + bias + resid.  1-D grid + XCD swizzle; gx=N/64.
// ---------------------------------------------------------------------------
__global__ __launch_bounds__(256)
void gemm_n64(const bf16* __restrict__ A, const bf16* __restrict__ B,
              const float* __restrict__ bias, const float* __restrict__ resid,
              float* __restrict__ outp, int M, int N, int K, int gx) {
    __shared__ bf16 As[3][128 * 64];
    __shared__ bf16 Bs[3][64 * 64];
    const int tid = threadIdx.x;
    const int lane = tid & 63, w = tid >> 6;
    const int grp = lane >> 4, c16 = lane & 15;
    const int wm = w * 32;
    const int nwg = gridDim.x, bid = blockIdx.x;
    const int sw = (bid & 7) * (nwg >> 3) + (bid >> 3);
    const int bm = (sw / gx) * 128, bn = (sw % gx) * 64;

    f32x4 acc[2][4];
    const f32x4 zero = {0.f, 0.f, 0.f, 0.f};
#pragma unroll
    for (int mi = 0; mi < 2; mi++)
#pragma unroll
        for (int ni = 0; ni < 4; ni++) acc[mi][ni] = zero;

#define STAGE64(bufi, k0)                                                           \
    {                                                                               \
        const int buf_ = (bufi);                                                    \
        const int koff_ = (k0);                                                     \
        _Pragma("unroll") for (int t_ = 0; t_ < 4; t_++) {                          \
            int s_ = t_ * 256 + tid;                                                \
            int row_ = s_ >> 3, db_ = s_ & 7;                                       \
            async_cp16(&As[buf_][s_ * 8], A + (size_t)(bm + row_) * K + koff_ + ((db_ ^ (row_ & 7)) << 3)); \
        }                                                                           \
        _Pragma("unroll") for (int t_ = 0; t_ < 2; t_++) {                          \
            int s_ = t_ * 256 + tid;                                                \
            int row_ = s_ >> 3, db_ = s_ & 7;                                       \
            async_cp16(&Bs[buf_][s_ * 8], B + (size_t)(bn + row_) * K + koff_ + ((db_ ^ (row_ & 7)) << 3)); \
        }                                                                           \
    }

#define COMPUTE64(bufi)                                                             \
    {                                                                               \
        const int buf_ = (bufi);                                                    \
        _Pragma("unroll") for (int kc_ = 0; kc_ < 2; kc_++) {                       \
            s16x8 af_[2], bfv_[4];                                                  \
            _Pragma("unroll") for (int mi_ = 0; mi_ < 2; mi_++) {                   \
                int r_ = wm + mi_ * 16 + c16;                                       \
                af_[mi_] = *(const s16x8*)&As[buf_][r_ * 64 + ((((kc_ << 2) | grp) ^ (r_ & 7)) << 3)]; \
            }                                                                       \
            _Pragma("unroll") for (int ni_ = 0; ni_ < 4; ni_++) {                   \
                int rb_ = ni_ * 16 + c16;                                           \
                bfv_[ni_] = *(const s16x8*)&Bs[buf_][rb_ * 64 + ((((kc_ << 2) | grp) ^ (rb_ & 7)) << 3)]; \
            }                                                                       \
            _Pragma("unroll") for (int mi_ = 0; mi_ < 2; mi_++)                     \
                _Pragma("unroll") for (int ni_ = 0; ni_ < 4; ni_++)                 \
                    acc[mi_][ni_] = __builtin_amdgcn_mfma_f32_16x16x32_bf16(af_[mi_], bfv_[ni_], acc[mi_][ni_], 0, 0, 0); \
        }                                                                           \
    }

#define WAITV12 asm volatile("s_waitcnt vmcnt(12)" ::: "memory")
#define WAITV6  asm volatile("s_waitcnt vmcnt(6)"  ::: "memory")
#define WAITV0  asm volatile("s_waitcnt vmcnt(0)"  ::: "memory")

#define STEP64(BQ, TQ)                                                              \
    {                                                                               \
        const int tq_ = (TQ);                                                       \
        COMPUTE64(BQ);                                                              \
        __builtin_amdgcn_s_barrier();        /* all waves done reading buf BQ */    \
        if (tq_ + 3 < nk) { STAGE64(BQ, (tq_ + 3) << 6); WAITV12; }                 \
        else if (tq_ + 2 < nk) { WAITV6; }                                          \
        else { WAITV0; }                     /* tile TQ+1 now complete */           \
        __builtin_amdgcn_s_barrier();        /* everyone's TQ+1 loads landed */     \
    }

    const int nk = K >> 6;
    STAGE64(0, 0);
    STAGE64(1, 64);
    STAGE64(2, 128);
    WAITV12;                                 // tile 0 complete
    __builtin_amdgcn_s_barrier();

    for (int t = 0; t < nk - 1; t += 3) {    // nk-1 divisible by 3
        STEP64(0, t);
        STEP64(1, t + 1);
        STEP64(2, t + 2);
    }
    COMPUTE64(0);                            // tile nk-1, (nk-1)%3 == 0

#undef STEP64
#undef WAITV12
#undef WAITV6
#undef WAITV0
#undef STAGE64
#undef COMPUTE64

#pragma unroll
    for (int mi = 0; mi < 2; mi++)
#pragma unroll
        for (int ni = 0; ni < 4; ni++) {
            int r0 = bm + wm + mi * 16 + grp * 4;
            int c  = bn + ni * 16 + c16;
            float bv = bias[c];
#pragma unroll
            for (int q = 0; q < 4; q++) {
                size_t idx = (size_t)(r0 + q) * N + c;
                outp[idx] = acc[mi][ni][q] + bv + resid[idx];
            }
        }
}

// ---------------------------------------------------------------------------
// LoRA: after_A[M,8] = h @ lora_A^T   (one block per row)
// ---------------------------------------------------------------------------
__global__ __launch_bounds__(256)
void lora_a_kernel(const bf16* __restrict__ h, const float* __restrict__ A,
                   float* __restrict__ afterA) {
    const int row = blockIdx.x, tid = threadIdx.x;
    float hv[4];
#pragma unroll
    for (int t = 0; t < 4; t++) hv[t] = __bfloat162float(h[(size_t)row * 1024 + tid * 4 + t]);
    float p[8];
#pragma unroll
    for (int r = 0; r < 8; r++) {
        float4 av = ((const float4*)(A + (size_t)r * 1024))[tid];
        p[r] = hv[0] * av.x + hv[1] * av.y + hv[2] * av.z + hv[3] * av.w;
    }
#pragma unroll
    for (int r = 0; r < 8; r++)
#pragma unroll
        for (int o = 32; o >= 1; o >>= 1) p[r] += __shfl_xor(p[r], o);
    __shared__ float red[4][8];
    int w = tid >> 6, lane = tid & 63;
    if (lane == 0) {
#pragma unroll
        for (int r = 0; r < 8; r++) red[w][r] = p[r];
    }
    __syncthreads();
    if (tid < 8) afterA[(size_t)row * 8 + tid] = red[0][tid] + red[1][tid] + red[2][tid] + red[3][tid];
}

// ---------------------------------------------------------------------------
// Flash attention, S-transposed, mfma_32x32x16, static-shift softmax.
// R4: softmax VALU diet — raw v_exp_f32 + v_cvt_pk_bf16_f32; j-loop
// unrolled 2x (compile-time LDS buffer index); s_setprio around MFMA (T5).
// ---------------------------------------------------------------------------
__global__ __launch_bounds__(256)
void attn_fused(const bf16* __restrict__ Qb, const bf16* __restrict__ Kb,
                const bf16* __restrict__ Vt, bf16* __restrict__ Og) {
    __shared__ bf16 Qs[128 * 64], Ks[2][64 * 64], Vs[2][64 * 64];
    const int tid = threadIdx.x;
    const int lane = tid & 63, w = tid >> 6;
    const int c32 = lane & 31, l5 = lane >> 5;
    const int bid = blockIdx.x;
    const int sw = (bid & 7) * 64 + (bid >> 3);   // XCD grouping (512 blocks)
    const int bh = sw >> 4, b = bh >> 4, h = bh & 15;
    const int i0 = (sw & 15) * 128;
    const int rowperm = (c32 & 19) | (((c32 >> 3) & 1) << 2) | (((c32 >> 2) & 1) << 3);

    const size_t qbase = (size_t)(bh * 2048 + i0) * 64;
    const size_t kbase = (size_t)bh * 2048 * 64;
    const size_t vbase = (size_t)bh * 64 * 2048;

#define STAGEKV(bufi, jv)                                                           \
    {                                                                               \
        const int buf_ = (bufi);                                                    \
        const int joff_ = (jv);                                                     \
        _Pragma("unroll") for (int t_ = 0; t_ < 2; t_++) {                          \
            int s_ = t_ * 256 + tid;                                                \
            int row_ = s_ >> 3, db_ = s_ & 7;                                       \
            int gb_ = (db_ ^ (row_ & 7)) << 3;                                      \
            async_cp16(&Ks[buf_][s_ * 8], Kb + kbase + (size_t)(joff_ + row_) * 64 + gb_); \
            async_cp16(&Vs[buf_][s_ * 8], Vt + vbase + (size_t)row_ * 2048 + joff_ + gb_); \
        }                                                                           \
    }

    // prologue: Q tile + first K/V tile in one stage, one barrier
#pragma unroll
    for (int t = 0; t < 4; t++) {
        int s = t * 256 + tid;
        int row = s >> 3, db = s & 7;
        async_cp16(&Qs[s * 8], Qb + qbase + row * 64 + ((db ^ (row & 7)) << 3));
    }
    STAGEKV(0, 0);
    __syncthreads();

    s16x8 qf[4];
    {
        int rq = w * 32 + c32;
#pragma unroll
        for (int kc = 0; kc < 4; kc++) {
            int db = 2 * kc + l5;
            qf[kc] = *(const s16x8*)&Qs[rq * 64 + ((db ^ (rq & 7)) << 3)];
        }
    }

    f32x16 Oq[2];
#pragma unroll
    for (int dq = 0; dq < 2; dq++)
#pragma unroll
        for (int r = 0; r < 16; r++) Oq[dq][r] = 0.f;
    float l_lane = 0.f;

// One attention tile: BUF is a compile-time literal (0/1) so all LDS read
// addresses are loop-invariant; JN is the tile index to prefetch (skip if >=32).
#define ATILE(BUF, JN)                                                              \
    {                                                                               \
        const int jn_ = (JN);                                                       \
        if (jn_ < 32) { STAGEKV((BUF) ^ 1, jn_ << 6); }                             \
        f32x16 Sq[2];                                                               \
        __builtin_amdgcn_s_setprio(1);                                              \
        _Pragma("unroll") for (int jq_ = 0; jq_ < 2; jq_++) {                       \
            _Pragma("unroll") for (int r_ = 0; r_ < 16; r_++) Sq[jq_][r_] = 0.f;    \
            int rk_ = jq_ * 32 + rowperm;                                           \
            _Pragma("unroll") for (int kc_ = 0; kc_ < 4; kc_++) {                   \
                int db_ = 2 * kc_ + l5;                                             \
                s16x8 af_ = *(const s16x8*)&Ks[BUF][rk_ * 64 + ((db_ ^ (rk_ & 7)) << 3)]; \
                Sq[jq_] = __builtin_amdgcn_mfma_f32_32x32x16_bf16(af_, qf[kc_], Sq[jq_], 0, 0, 0); \
            }                                                                       \
        }                                                                           \
        __builtin_amdgcn_s_setprio(0);                                              \
        s16x8 pf_[4];                                                               \
        _Pragma("unroll") for (int kc_ = 0; kc_ < 4; kc_++) {                       \
            union { s16x8 v; unsigned u4[4]; } u_;                                  \
            _Pragma("unroll") for (int pr_ = 0; pr_ < 4; pr_++) {                   \
                float a_ = Sq[kc_ >> 1][8 * (kc_ & 1) + 2 * pr_];                   \
                float b_ = Sq[kc_ >> 1][8 * (kc_ & 1) + 2 * pr_ + 1];               \
                float pa_, pb_;                                                     \
                asm("v_exp_f32 %0, %1" : "=v"(pa_) : "v"(a_));                      \
                asm("v_exp_f32 %0, %1" : "=v"(pb_) : "v"(b_));                      \
                l_lane += pa_; l_lane += pb_;                                       \
                unsigned pk_;                                                       \
                asm("v_cvt_pk_bf16_f32 %0, %1, %2" : "=v"(pk_) : "v"(pa_), "v"(pb_)); \
                u_.u4[pr_] = pk_;                                                   \
            }                                                                       \
            pf_[kc_] = u_.v;                                                        \
        }                                                                           \
        __builtin_amdgcn_s_setprio(1);                                              \
        _Pragma("unroll") for (int dq_ = 0; dq_ < 2; dq_++) {                       \
            int rd_ = dq_ * 32 + c32;                                               \
            _Pragma("unroll") for (int kc_ = 0; kc_ < 4; kc_++) {                   \
                int jb_ = 2 * kc_ + l5;                                             \
                s16x8 af_ = *(const s16x8*)&Vs[BUF][rd_ * 64 + ((jb_ ^ (rd_ & 7)) << 3)]; \
                Oq[dq_] = __builtin_amdgcn_mfma_f32_32x32x16_bf16(af_, pf_[kc_], Oq[dq_], 0, 0, 0); \
            }                                                                       \
        }                                                                           \
        __builtin_amdgcn_s_setprio(0);                                              \
        __syncthreads();                                                            \
    }

    for (int jt = 0; jt < 32; jt += 2) {
        ATILE(0, jt + 1);
        ATILE(1, jt + 2);
    }
#undef ATILE
#undef STAGEKV

    float l = l_lane + __shfl_xor(l_lane, 32);
    float inv = 1.0f / fmaxf(l, 1e-35f);
    int i = i0 + w * 32 + c32;
    size_t obase = (size_t)(b * 2048 + i) * 1024 + h * 64;
#pragma unroll
    for (int dq = 0; dq < 2; dq++)
#pragma unroll
        for (int rg = 0; rg < 4; rg++) {
            union { bf16 e[4]; uint2 u; } pk;
#pragma unroll
            for (int c = 0; c < 4; c++)
                pk.e[c] = __float2bfloat16(Oq[dq][rg * 4 + c] * inv);
            int d0 = dq * 32 + l5 * 4 + rg * 8;
            *(uint2*)&Og[obase + d0] = pk.u;
        }
}

// ---------------------------------------------------------------------------
extern "C" void kernel_launch(void* const* d_in, const int* in_sizes, int n_in,
                              void* d_out, int out_size, void* d_ws, size_t ws_size,
                              hipStream_t stream) {
    const float* x     = (const float*)d_in[0];
    const float* pos   = (const float*)d_in[1];
    const float* Wqkv  = (const float*)d_in[2];
    const float* bqkv  = (const float*)d_in[3];
    const float* loraA = (const float*)d_in[4];
    const float* loraB = (const float*)d_in[5];
    const float* Wproj = (const float*)d_in[6];
    const float* bproj = (const float*)d_in[7];
    const float* ln1g  = (const float*)d_in[8];
    const float* ln1b  = (const float*)d_in[9];
    const float* ln2g  = (const float*)d_in[10];
    const float* ln2b  = (const float*)d_in[11];
    const float* W1    = (const float*)d_in[12];
    const float* b1    = (const float*)d_in[13];
    const float* W2    = (const float*)d_in[14];
    const float* b2    = (const float*)d_in[15];

    char* ws = (char*)d_ws;
    float* x1     = (float*)(ws + 0);            // 16 MB
    bf16*  hbuf   = (bf16*) (ws + 16777216);     // 8 MB
    bf16*  gbuf   = (bf16*) (ws + 50331648);     // 32 MB
    float* afterA = (float*)(ws + 83886080);     // 128 KB
    bf16*  Qb     = (bf16*) (ws + 84017152);     // 8 MB
    bf16*  Kb     = (bf16*) (ws + 92405760);     // 8 MB
    bf16*  Vt     = (bf16*) (ws + 100794368);    // 8 MB
    bf16*  Obf    = (bf16*) (ws + 109182976);    // 8 MB
    bf16*  Wqkvb  = (bf16*) (ws + 117571584);    // 6 MB
    bf16*  Wprojb = (bf16*) (ws + 123863040);    // 2 MB
    bf16*  W1b    = (bf16*) (ws + 125960192);    // 8 MB
    bf16*  W2b    = (bf16*) (ws + 134348800);    // 8 MB (end ~142.7 MB)

    cvt_all<<<12288, 256, 0, stream>>>(Wqkv, Wproj, W1, W2, Wqkvb, Wprojb, W1b, W2b);

    ln_kernel<true><<<4096, 256, 0, stream>>>(x, pos, ln1g, ln1b, x1, hbuf);

    lora_a_kernel<<<4096, 256, 0, stream>>>(hbuf, loraA, afterA);

    // QKV fused: M=4096, N=3072, K=1024 -> 192 blocks (gx=12); writes Qb/Kb/Vt
    gemm_bk64<1><<<192, 512, 0, stream>>>(hbuf, Wqkvb, bqkv, nullptr,
                                          afterA, loraB, Qb, Kb, Vt,
                                          4096, 3072, 1024, 12);

    attn_fused<<<512, 256, 0, stream>>>(Qb, Kb, Vt, Obf);

    // proj: M=4096, N=1024, K=1024 -> 512 blocks (gx=16)
    gemm_n64<<<512, 256, 0, stream>>>(Obf, Wprojb, bproj, x1, x1, 4096, 1024, 1024, 16);

    ln_kernel<false><<<4096, 256, 0, stream>>>(x1, nullptr, ln2g, ln2b, nullptr, hbuf);

    // W1: M=4096, N=4096, K=1024 -> 256 blocks (gx=16)
    gemm_bk64<2><<<256, 512, 0, stream>>>(hbuf, W1b, b1, gbuf,
                                          nullptr, nullptr, nullptr, nullptr, nullptr,
                                          4096, 4096, 1024, 16);

    // W2: M=4096, N=1024, K=4096 -> 512 blocks (gx=16)
    gemm_n64<<<512, 256, 0, stream>>>(gbuf, W2b, b2, x1, (float*)d_out, 4096, 1024, 4096, 16);

    (void)in_sizes; (void)n_in; (void)out_size; (void)ws_size;
}

// Round 13
// 360.236 us; speedup vs baseline: 1.0330x; 1.0330x over previous
//
#include <hip/hip_runtime.h>
#include <hip/hip_bf16.h>
#include <math.h>

typedef __hip_bfloat16 bf16;
typedef __attribute__((ext_vector_type(4))) float f32x4;
typedef __attribute__((ext_vector_type(16))) float f32x16;
typedef __attribute__((ext_vector_type(8))) short s16x8;

__device__ __forceinline__ void async_cp16(void* lds, const void* g) {
    __builtin_amdgcn_global_load_lds((const __attribute__((address_space(1))) void*)g,
                                     (__attribute__((address_space(3))) void*)lds, 16, 0, 0);
}

// tanh-form GELU (max |diff| vs exact-erf gelu ~3e-3; threshold 0.154)
__device__ __forceinline__ float gelu_fast(float x) {
    float y = 1.5957691216f * (x + 0.044715f * x * x * x);
    float t = __expf(y);
    float th = 1.0f - 2.0f / (t + 1.0f);
    return 0.5f * x * (1.0f + th);
}

// ---------------------------------------------------------------------------
// fused f32 -> bf16 cast of all four weight matrices (one launch)
// ---------------------------------------------------------------------------
__global__ __launch_bounds__(256)
void cvt_all(const float* __restrict__ w0, const float* __restrict__ w1,
             const float* __restrict__ w2, const float* __restrict__ w3,
             bf16* __restrict__ o0, bf16* __restrict__ o1,
             bf16* __restrict__ o2, bf16* __restrict__ o3) {
    int i = blockIdx.x * 256 + threadIdx.x;
    const float* src; bf16* dst; int j = i;
    if (j < 786432)            { src = w0; dst = o0; }
    else if (j < 1048576)      { j -= 786432;  src = w1; dst = o1; }
    else if (j < 2097152)      { j -= 1048576; src = w2; dst = o2; }
    else                       { j -= 2097152; src = w3; dst = o3; }
    float4 v = ((const float4*)src)[j];
    union { bf16 o[4]; uint2 u; } pk;
    pk.o[0] = __float2bfloat16(v.x); pk.o[1] = __float2bfloat16(v.y);
    pk.o[2] = __float2bfloat16(v.z); pk.o[3] = __float2bfloat16(v.w);
    ((uint2*)dst)[j] = pk.u;
}

// ---------------------------------------------------------------------------
// LayerNorm. ADD variant: x1 = x + pos first, AND fused lora_a epilogue
// (R13): after_A[row][0:8] = h_row @ loraA^T computed from the f32 LN
// output already in registers (one fewer kernel, -8 MB hbuf re-read,
// and closer to the f32 reference than the old bf16-input lora_a).
// ---------------------------------------------------------------------------
template <bool ADD>
__global__ __launch_bounds__(256)
void ln_kernel(const float* __restrict__ xin, const float* __restrict__ pos,
               const float* __restrict__ gam, const float* __restrict__ bet,
               float* __restrict__ x1, bf16* __restrict__ hout,
               const float* __restrict__ loraA, float* __restrict__ afterA) {
    const int row = blockIdx.x, tid = threadIdx.x;
    const size_t off = (size_t)row * 1024;
    float4 v = ((const float4*)(xin + off))[tid];
    if constexpr (ADD) {
        float4 p = ((const float4*)(pos + off))[tid];
        v.x += p.x; v.y += p.y; v.z += p.z; v.w += p.w;
        ((float4*)(x1 + off))[tid] = v;
    }
    float s  = v.x + v.y + v.z + v.w;
    float s2 = v.x*v.x + v.y*v.y + v.z*v.z + v.w*v.w;
#pragma unroll
    for (int o = 32; o >= 1; o >>= 1) { s += __shfl_xor(s, o); s2 += __shfl_xor(s2, o); }
    __shared__ float sS[4], sS2[4];
    int w = tid >> 6, lane = tid & 63;
    if (lane == 0) { sS[w] = s; sS2[w] = s2; }
    __syncthreads();
    float mean = (sS[0] + sS[1] + sS[2] + sS[3]) * (1.f / 1024.f);
    float e2   = (sS2[0] + sS2[1] + sS2[2] + sS2[3]) * (1.f / 1024.f);
    float rstd = rsqrtf(e2 - mean * mean + 1e-5f);
    float4 gv = ((const float4*)gam)[tid], bv = ((const float4*)bet)[tid];
    float h0 = (v.x - mean) * rstd * gv.x + bv.x;
    float h1 = (v.y - mean) * rstd * gv.y + bv.y;
    float h2 = (v.z - mean) * rstd * gv.z + bv.z;
    float h3 = (v.w - mean) * rstd * gv.w + bv.w;
    bf16* ho = hout + off + tid * 4;
    ho[0] = __float2bfloat16(h0);
    ho[1] = __float2bfloat16(h1);
    ho[2] = __float2bfloat16(h2);
    ho[3] = __float2bfloat16(h3);
    if constexpr (ADD) {
        // fused lora_a: 8 dot products of the f32 h-row against loraA rows
        float p[8];
#pragma unroll
        for (int r = 0; r < 8; r++) {
            float4 av = ((const float4*)(loraA + (size_t)r * 1024))[tid];
            p[r] = h0 * av.x + h1 * av.y + h2 * av.z + h3 * av.w;
        }
#pragma unroll
        for (int r = 0; r < 8; r++)
#pragma unroll
            for (int o = 32; o >= 1; o >>= 1) p[r] += __shfl_xor(p[r], o);
        __shared__ float red[4][8];
        if (lane == 0) {
#pragma unroll
            for (int r = 0; r < 8; r++) red[w][r] = p[r];
        }
        __syncthreads();
        if (tid < 8) afterA[(size_t)row * 8 + tid] = red[0][tid] + red[1][tid] + red[2][tid] + red[3][tid];
    }
}

// ---------------------------------------------------------------------------
// GEMM 256x256 tile, BK=64 — R9 skeleton (separate As[2]/Bs[2]; R11's merged
// SM[4] made the allocator spill the 128-float accumulator at 128 VGPR).
// 512 threads, 8 waves 2M x 4N, wave tile 128x64 (acc[8][4]), double-
// buffered counted-vmcnt depth-1:
//   compute(buf) ; s_barrier ; stage(t+2 -> buf) ; s_waitcnt vmcnt(8) ;
//   s_barrier
// LDS 2x64 = 128 KB -> 1 block/CU, 2 waves/SIMD. REQUIRES nk even.
// 1-D grid + bijective XCD chunk swizzle (nwg % 8 == 0); gx = N/256.
// MODE 1 = fused QKV epilogue: Qb (LoRA-q + 0.125*log2e), Kb, and Vt
// TRANSPOSED via a TWO-PASS 64 KB window in Bs (256 feat x 128 tok per
// pass). Swizzle ^(fl&7)<<3 -> 2-way max (free); coalesced Vt stores.
// MODE 2: out = gelu(acc + bias)    (W1)
// ---------------------------------------------------------------------------
template <int MODE>
__global__ __launch_bounds__(512, 2)
void gemm_bk64(const bf16* __restrict__ A, const bf16* __restrict__ B,
               const float* __restrict__ bias, bf16* __restrict__ outp,
               const float* __restrict__ afterA, const float* __restrict__ loraB,
               bf16* __restrict__ Qb, bf16* __restrict__ Kb, bf16* __restrict__ Vt,
               int M, int N, int K, int gx) {
    __shared__ bf16 As[2][256 * 64];
    __shared__ bf16 Bs[2][256 * 64];
    const int tid = threadIdx.x;
    const int lane = tid & 63, w = tid >> 6;
    const int grp = lane >> 4, c16 = lane & 15;
    const int wm = (w & 1) * 128, wn = (w >> 1) * 64;   // 8 waves: 2M x 4N
    const int nwg = gridDim.x, bid = blockIdx.x;
    const int sw = (bid & 7) * (nwg >> 3) + (bid >> 3);   // XCD chunk swizzle
    const int bm = (sw / gx) * 256, bn = (sw % gx) * 256;

    f32x4 acc[8][4];
    const f32x4 zero = {0.f, 0.f, 0.f, 0.f};
#pragma unroll
    for (int mi = 0; mi < 8; mi++)
#pragma unroll
        for (int ni = 0; ni < 4; ni++) acc[mi][ni] = zero;

#define STAGE256(bufi, k0)                                                          \
    {                                                                               \
        const int buf_ = (bufi);                                                    \
        const int koff_ = (k0);                                                     \
        _Pragma("unroll") for (int t_ = 0; t_ < 4; t_++) {                          \
            int s_ = t_ * 512 + tid;                                                \
            int row_ = s_ >> 3, db_ = s_ & 7;                                       \
            int gb_ = (db_ ^ (row_ & 7)) << 3;                                      \
            async_cp16(&As[buf_][s_ * 8], A + (size_t)(bm + row_) * K + koff_ + gb_); \
            async_cp16(&Bs[buf_][s_ * 8], B + (size_t)(bn + row_) * K + koff_ + gb_); \
        }                                                                           \
    }

#define COMPUTE256(bufi)                                                            \
    {                                                                               \
        const int buf_ = (bufi);                                                    \
        _Pragma("unroll") for (int kc_ = 0; kc_ < 2; kc_++) {                       \
            s16x8 af_[8], bfv_[4];                                                  \
            _Pragma("unroll") for (int mi_ = 0; mi_ < 8; mi_++) {                   \
                int r_ = wm + mi_ * 16 + c16;                                       \
                af_[mi_] = *(const s16x8*)&As[buf_][r_ * 64 + ((((kc_ << 2) | grp) ^ (r_ & 7)) << 3)]; \
            }                                                                       \
            _Pragma("unroll") for (int ni_ = 0; ni_ < 4; ni_++) {                   \
                int r_ = wn + ni_ * 16 + c16;                                       \
                bfv_[ni_] = *(const s16x8*)&Bs[buf_][r_ * 64 + ((((kc_ << 2) | grp) ^ (r_ & 7)) << 3)]; \
            }                                                                       \
            _Pragma("unroll") for (int mi_ = 0; mi_ < 8; mi_++)                     \
                _Pragma("unroll") for (int ni_ = 0; ni_ < 4; ni_++)                 \
                    acc[mi_][ni_] = __builtin_amdgcn_mfma_f32_16x16x32_bf16(af_[mi_], bfv_[ni_], acc[mi_][ni_], 0, 0, 0); \
        }                                                                           \
    }

#define WAITV8 asm volatile("s_waitcnt vmcnt(8)" ::: "memory")
#define WAITV0 asm volatile("s_waitcnt vmcnt(0)" ::: "memory")

// One pipelined K-step. Invariant at entry: tile TQ complete in buf BQ;
// tile TQ+1 in flight (8 loads outstanding per thread).
#define STEP256(BQ, TQ)                                                             \
    {                                                                               \
        const int tq_ = (TQ);                                                       \
        COMPUTE256(BQ);                                                             \
        __builtin_amdgcn_s_barrier();        /* all waves done reading buf BQ */    \
        if (tq_ + 2 < nk) { STAGE256(BQ, (tq_ + 2) << 6); WAITV8; }                 \
        else { WAITV0; }                     /* tile TQ+1 now complete */           \
        __builtin_amdgcn_s_barrier();        /* everyone's TQ+1 loads landed */     \
    }

    const int nk = K >> 6;                   // K=1024 -> nk=16 (even)
    STAGE256(0, 0);
    STAGE256(1, 64);
    WAITV8;                                  // tile 0 complete
    __builtin_amdgcn_s_barrier();

    for (int t = 0; t < nk - 2; t += 2) {
        STEP256(0, t);
        STEP256(1, t + 1);
    }
    STEP256(0, nk - 2);                      // stages nothing; WAITV0
    COMPUTE256(1);                           // tile nk-1 in buf 1

#undef STEP256
#undef WAITV8
#undef WAITV0
#undef STAGE256
#undef COMPUTE256

    if constexpr (MODE == 1) {
        // fused QKV epilogue. role: 0=q, 1=k, 2=v (block-uniform).
        const int role = bn >> 10;
        const int g_b  = bm >> 11;           // batch index (rows 256-aligned)
        if (role == 2) {
            // v: bias + LoRA, transpose through Bs (64 KB window), 2 passes.
            char* tp = (char*)&Bs[0][0];     // 256 feat x 128 tok bf16, 256B rows
            const int tokb = bm & 2047;
#pragma unroll
            for (int pass = 0; pass < 2; pass++) {
                if ((wm >> 7) == pass) {     // this wave's tokens in this half
#pragma unroll
                    for (int mi = 0; mi < 8; mi++) {
                        float4 aA4[4];
#pragma unroll
                        for (int q = 0; q < 4; q++) {
                            int grow = bm + wm + mi * 16 + grp * 4 + q;
                            aA4[q] = ((const float4*)afterA)[(size_t)grow * 2 + 1];
                        }
#pragma unroll
                        for (int ni = 0; ni < 4; ni++) {
                            int fl = wn + ni * 16 + c16;      // feature 0..255
                            int cr = (bn & 1023) + fl;
                            float bv = bias[bn + fl];
                            float4 bw = ((const float4*)loraB)[1024 + cr];
                            union { bf16 e[4]; uint2 u; } pk;
#pragma unroll
                            for (int q = 0; q < 4; q++) {
                                float dv = (aA4[q].x*bw.x + aA4[q].y*bw.y + aA4[q].z*bw.z + aA4[q].w*bw.w) * 0.25f;
                                pk.e[q] = __float2bfloat16(acc[mi][ni][q] + bv + dv);
                            }
                            int tl = mi * 16 + grp * 4;       // 0..124 in half
                            int off = (fl * 256 + tl * 2) ^ ((fl & 7) << 3);
                            *(uint2*)(tp + off) = pk.u;
                        }
                    }
                }
                __syncthreads();
#pragma unroll
                for (int it = 0; it < 16; it++) {
                    int s = it * 512 + tid;
                    int fl = s >> 5, c4 = s & 31;             // 32 lanes = 1 feat
                    int off = (fl * 256 + c4 * 8) ^ ((fl & 7) << 3);
                    uint2 v = *(uint2*)(tp + off);
                    int cr = (bn & 1023) + fl;
                    int h = cr >> 6, d = cr & 63;
                    *(uint2*)&Vt[((size_t)(g_b * 16 + h) * 64 + d) * 2048 + tokb + pass * 128 + c4 * 4] = v;
                }
                if (pass == 0) __syncthreads();
            }
        } else if (role == 0) {
#pragma unroll
            for (int mi = 0; mi < 8; mi++) {
                float4 aA4[4];
#pragma unroll
                for (int q = 0; q < 4; q++) {
                    int grow = bm + wm + mi * 16 + grp * 4 + q;
                    aA4[q] = ((const float4*)afterA)[(size_t)grow * 2];
                }
#pragma unroll
                for (int ni = 0; ni < 4; ni++) {
                    int c  = bn + wn + ni * 16 + c16;
                    int cr = c & 1023;
                    int h  = cr >> 6, d = cr & 63;
                    float bv = bias[c];
                    float4 bw = ((const float4*)loraB)[cr];
#pragma unroll
                    for (int q = 0; q < 4; q++) {
                        int grow = bm + wm + mi * 16 + grp * 4 + q;
                        float dq = (aA4[q].x*bw.x + aA4[q].y*bw.y + aA4[q].z*bw.z + aA4[q].w*bw.w) * 0.25f;
                        float v = (acc[mi][ni][q] + bv + dq) * 0.18033688011f;  // 0.125*log2(e)
                        Qb[((size_t)(g_b * 16 + h) * 2048 + (grow & 2047)) * 64 + d] = __float2bfloat16(v);
                    }
                }
            }
        } else {
#pragma unroll
            for (int mi = 0; mi < 8; mi++)
#pragma unroll
                for (int ni = 0; ni < 4; ni++) {
                    int c  = bn + wn + ni * 16 + c16;
                    int cr = c & 1023;
                    int h  = cr >> 6, d = cr & 63;
                    float bv = bias[c];
#pragma unroll
                    for (int q = 0; q < 4; q++) {
                        int grow = bm + wm + mi * 16 + grp * 4 + q;
                        Kb[((size_t)(g_b * 16 + h) * 2048 + (grow & 2047)) * 64 + d] =
                            __float2bfloat16(acc[mi][ni][q] + bv);
                    }
                }
        }
    } else {
#pragma unroll
        for (int mi = 0; mi < 8; mi++)
#pragma unroll
            for (int ni = 0; ni < 4; ni++) {
                int r0 = bm + wm + mi * 16 + grp * 4;
                int c  = bn + wn + ni * 16 + c16;
                float bv = bias[c];
#pragma unroll
                for (int q = 0; q < 4; q++) {
                    size_t idx = (size_t)(r0 + q) * N + c;
                    float v = acc[mi][ni][q] + bv;
                    if constexpr (MODE == 2) v = gelu_fast(v);
                    outp[idx] = __float2bfloat16(v);
                }
            }
    }
}

// ---------------------------------------------------------------------------
// GEMM 128x64 tile, BK=64 — R7 config (proven): TRIPLE-BUFFERED counted-
// vmcnt pipeline. REQUIRES (K/64 - 1) % 3 == 0 (K=1024/4096 OK).
// Epilogue: out fp32 = acc + bias + resid.  1-D grid + XCD swizzle; gx=N/64.
// ---------------------------------------------------------------------------
__global__ __launch_bounds__(256)
void gemm_n64(const bf16* __restrict__ A, const bf16* __restrict__ B,
              const float* __restrict__ bias, const float* __restrict__ resid,
              float* __restrict__ outp, int M, int N, int K, int gx) {
    __shared__ bf16 As[3][128 * 64];
    __shared__ bf16 Bs[3][64 * 64];
    const int tid = threadIdx.x;
    const int lane = tid & 63, w = tid >> 6;
    const int grp = lane >> 4, c16 = lane & 15;
    const int wm = w * 32;
    const int nwg = gridDim.x, bid = blockIdx.x;
    const int sw = (bid & 7) * (nwg >> 3) + (bid >> 3);
    const int bm = (sw / gx) * 128, bn = (sw % gx) * 64;

    f32x4 acc[2][4];
    const f32x4 zero = {0.f, 0.f, 0.f, 0.f};
#pragma unroll
    for (int mi = 0; mi < 2; mi++)
#pragma unroll
        for (int ni = 0; ni < 4; ni++) acc[mi][ni] = zero;

#define STAGE64(bufi, k0)                                                           \
    {                                                                               \
        const int buf_ = (bufi);                                                    \
        const int koff_ = (k0);                                                     \
        _Pragma("unroll") for (int t_ = 0; t_ < 4; t_++) {                          \
            int s_ = t_ * 256 + tid;                                                \
            int row_ = s_ >> 3, db_ = s_ & 7;                                       \
            async_cp16(&As[buf_][s_ * 8], A + (size_t)(bm + row_) * K + koff_ + ((db_ ^ (row_ & 7)) << 3)); \
        }                                                                           \
        _Pragma("unroll") for (int t_ = 0; t_ < 2; t_++) {                          \
            int s_ = t_ * 256 + tid;                                                \
            int row_ = s_ >> 3, db_ = s_ & 7;                                       \
            async_cp16(&Bs[buf_][s_ * 8], B + (size_t)(bn + row_) * K + koff_ + ((db_ ^ (row_ & 7)) << 3)); \
        }                                                                           \
    }

#define COMPUTE64(bufi)                                                             \
    {                                                                               \
        const int buf_ = (bufi);                                                    \
        _Pragma("unroll") for (int kc_ = 0; kc_ < 2; kc_++) {                       \
            s16x8 af_[2], bfv_[4];                                                  \
            _Pragma("unroll") for (int mi_ = 0; mi_ < 2; mi_++) {                   \
                int r_ = wm + mi_ * 16 + c16;                                       \
                af_[mi_] = *(const s16x8*)&As[buf_][r_ * 64 + ((((kc_ << 2) | grp) ^ (r_ & 7)) << 3)]; \
            }                                                                       \
            _Pragma("unroll") for (int ni_ = 0; ni_ < 4; ni_++) {                   \
                int rb_ = ni_ * 16 + c16;                                           \
                bfv_[ni_] = *(const s16x8*)&Bs[buf_][rb_ * 64 + ((((kc_ << 2) | grp) ^ (rb_ & 7)) << 3)]; \
            }                                                                       \
            _Pragma("unroll") for (int mi_ = 0; mi_ < 2; mi_++)                     \
                _Pragma("unroll") for (int ni_ = 0; ni_ < 4; ni_++)                 \
                    acc[mi_][ni_] = __builtin_amdgcn_mfma_f32_16x16x32_bf16(af_[mi_], bfv_[ni_], acc[mi_][ni_], 0, 0, 0); \
        }                                                                           \
    }

#define WAITV12 asm volatile("s_waitcnt vmcnt(12)" ::: "memory")
#define WAITV6  asm volatile("s_waitcnt vmcnt(6)"  ::: "memory")
#define WAITV0  asm volatile("s_waitcnt vmcnt(0)"  ::: "memory")

#define STEP64(BQ, TQ)                                                              \
    {                                                                               \
        const int tq_ = (TQ);                                                       \
        COMPUTE64(BQ);                                                              \
        __builtin_amdgcn_s_barrier();        /* all waves done reading buf BQ */    \
        if (tq_ + 3 < nk) { STAGE64(BQ, (tq_ + 3) << 6); WAITV12; }                 \
        else if (tq_ + 2 < nk) { WAITV6; }                                          \
        else { WAITV0; }                     /* tile TQ+1 now complete */           \
        __builtin_amdgcn_s_barrier();        /* everyone's TQ+1 loads landed */     \
    }

    const int nk = K >> 6;
    STAGE64(0, 0);
    STAGE64(1, 64);
    STAGE64(2, 128);
    WAITV12;                                 // tile 0 complete
    __builtin_amdgcn_s_barrier();

    for (int t = 0; t < nk - 1; t += 3) {    // nk-1 divisible by 3
        STEP64(0, t);
        STEP64(1, t + 1);
        STEP64(2, t + 2);
    }
    COMPUTE64(0);                            // tile nk-1, (nk-1)%3 == 0

#undef STEP64
#undef WAITV12
#undef WAITV6
#undef WAITV0
#undef STAGE64
#undef COMPUTE64

#pragma unroll
    for (int mi = 0; mi < 2; mi++)
#pragma unroll
        for (int ni = 0; ni < 4; ni++) {
            int r0 = bm + wm + mi * 16 + grp * 4;
            int c  = bn + ni * 16 + c16;
            float bv = bias[c];
#pragma unroll
            for (int q = 0; q < 4; q++) {
                size_t idx = (size_t)(r0 + q) * N + c;
                outp[idx] = acc[mi][ni][q] + bv + resid[idx];
            }
        }
}

// ---------------------------------------------------------------------------
// Flash attention, S-transposed, mfma_32x32x16, static-shift softmax.
// R4: softmax VALU diet — raw v_exp_f32 + v_cvt_pk_bf16_f32; j-loop
// unrolled 2x (compile-time LDS buffer index); s_setprio around MFMA (T5).
// ---------------------------------------------------------------------------
__global__ __launch_bounds__(256)
void attn_fused(const bf16* __restrict__ Qb, const bf16* __restrict__ Kb,
                const bf16* __restrict__ Vt, bf16* __restrict__ Og) {
    __shared__ bf16 Qs[128 * 64], Ks[2][64 * 64], Vs[2][64 * 64];
    const int tid = threadIdx.x;
    const int lane = tid & 63, w = tid >> 6;
    const int c32 = lane & 31, l5 = lane >> 5;
    const int bid = blockIdx.x;
    const int sw = (bid & 7) * 64 + (bid >> 3);   // XCD grouping (512 blocks)
    const int bh = sw >> 4, b = bh >> 4, h = bh & 15;
    const int i0 = (sw & 15) * 128;
    const int rowperm = (c32 & 19) | (((c32 >> 3) & 1) << 2) | (((c32 >> 2) & 1) << 3);

    const size_t qbase = (size_t)(bh * 2048 + i0) * 64;
    const size_t kbase = (size_t)bh * 2048 * 64;
    const size_t vbase = (size_t)bh * 64 * 2048;

#define STAGEKV(bufi, jv)                                                           \
    {                                                                               \
        const int buf_ = (bufi);                                                    \
        const int joff_ = (jv);                                                     \
        _Pragma("unroll") for (int t_ = 0; t_ < 2; t_++) {                          \
            int s_ = t_ * 256 + tid;                                                \
            int row_ = s_ >> 3, db_ = s_ & 7;                                       \
            int gb_ = (db_ ^ (row_ & 7)) << 3;                                      \
            async_cp16(&Ks[buf_][s_ * 8], Kb + kbase + (size_t)(joff_ + row_) * 64 + gb_); \
            async_cp16(&Vs[buf_][s_ * 8], Vt + vbase + (size_t)row_ * 2048 + joff_ + gb_); \
        }                                                                           \
    }

    // prologue: Q tile + first K/V tile in one stage, one barrier
#pragma unroll
    for (int t = 0; t < 4; t++) {
        int s = t * 256 + tid;
        int row = s >> 3, db = s & 7;
        async_cp16(&Qs[s * 8], Qb + qbase + row * 64 + ((db ^ (row & 7)) << 3));
    }
    STAGEKV(0, 0);
    __syncthreads();

    s16x8 qf[4];
    {
        int rq = w * 32 + c32;
#pragma unroll
        for (int kc = 0; kc < 4; kc++) {
            int db = 2 * kc + l5;
            qf[kc] = *(const s16x8*)&Qs[rq * 64 + ((db ^ (rq & 7)) << 3)];
        }
    }

    f32x16 Oq[2];
#pragma unroll
    for (int dq = 0; dq < 2; dq++)
#pragma unroll
        for (int r = 0; r < 16; r++) Oq[dq][r] = 0.f;
    float l_lane = 0.f;

// One attention tile: BUF is a compile-time literal (0/1) so all LDS read
// addresses are loop-invariant; JN is the tile index to prefetch (skip if >=32).
#define ATILE(BUF, JN)                                                              \
    {                                                                               \
        const int jn_ = (JN);                                                       \
        if (jn_ < 32) { STAGEKV((BUF) ^ 1, jn_ << 6); }                             \
        f32x16 Sq[2];                                                               \
        __builtin_amdgcn_s_setprio(1);                                              \
        _Pragma("unroll") for (int jq_ = 0; jq_ < 2; jq_++) {                       \
            _Pragma("unroll") for (int r_ = 0; r_ < 16; r_++) Sq[jq_][r_] = 0.f;    \
            int rk_ = jq_ * 32 + rowperm;                                           \
            _Pragma("unroll") for (int kc_ = 0; kc_ < 4; kc_++) {                   \
                int db_ = 2 * kc_ + l5;                                             \
                s16x8 af_ = *(const s16x8*)&Ks[BUF][rk_ * 64 + ((db_ ^ (rk_ & 7)) << 3)]; \
                Sq[jq_] = __builtin_amdgcn_mfma_f32_32x32x16_bf16(af_, qf[kc_], Sq[jq_], 0, 0, 0); \
            }                                                                       \
        }                                                                           \
        __builtin_amdgcn_s_setprio(0);                                              \
        s16x8 pf_[4];                                                               \
        _Pragma("unroll") for (int kc_ = 0; kc_ < 4; kc_++) {                       \
            union { s16x8 v; unsigned u4[4]; } u_;                                  \
            _Pragma("unroll") for (int pr_ = 0; pr_ < 4; pr_++) {                   \
                float a_ = Sq[kc_ >> 1][8 * (kc_ & 1) + 2 * pr_];                   \
                float b_ = Sq[kc_ >> 1][8 * (kc_ & 1) + 2 * pr_ + 1];               \
                float pa_, pb_;                                                     \
                asm("v_exp_f32 %0, %1" : "=v"(pa_) : "v"(a_));                      \
                asm("v_exp_f32 %0, %1" : "=v"(pb_) : "v"(b_));                      \
                l_lane += pa_; l_lane += pb_;                                       \
                unsigned pk_;                                                       \
                asm("v_cvt_pk_bf16_f32 %0, %1, %2" : "=v"(pk_) : "v"(pa_), "v"(pb_)); \
                u_.u4[pr_] = pk_;                                                   \
            }                                                                       \
            pf_[kc_] = u_.v;                                                        \
        }                                                                           \
        __builtin_amdgcn_s_setprio(1);                                              \
        _Pragma("unroll") for (int dq_ = 0; dq_ < 2; dq_++) {                       \
            int rd_ = dq_ * 32 + c32;                                               \
            _Pragma("unroll") for (int kc_ = 0; kc_ < 4; kc_++) {                   \
                int jb_ = 2 * kc_ + l5;                                             \
                s16x8 af_ = *(const s16x8*)&Vs[BUF][rd_ * 64 + ((jb_ ^ (rd_ & 7)) << 3)]; \
                Oq[dq_] = __builtin_amdgcn_mfma_f32_32x32x16_bf16(af_, pf_[kc_], Oq[dq_], 0, 0, 0); \
            }                                                                       \
        }                                                                           \
        __builtin_amdgcn_s_setprio(0);                                              \
        __syncthreads();                                                            \
    }

    for (int jt = 0; jt < 32; jt += 2) {
        ATILE(0, jt + 1);
        ATILE(1, jt + 2);
    }
#undef ATILE
#undef STAGEKV

    float l = l_lane + __shfl_xor(l_lane, 32);
    float inv = 1.0f / fmaxf(l, 1e-35f);
    int i = i0 + w * 32 + c32;
    size_t obase = (size_t)(b * 2048 + i) * 1024 + h * 64;
#pragma unroll
    for (int dq = 0; dq < 2; dq++)
#pragma unroll
        for (int rg = 0; rg < 4; rg++) {
            union { bf16 e[4]; uint2 u; } pk;
#pragma unroll
            for (int c = 0; c < 4; c++)
                pk.e[c] = __float2bfloat16(Oq[dq][rg * 4 + c] * inv);
            int d0 = dq * 32 + l5 * 4 + rg * 8;
            *(uint2*)&Og[obase + d0] = pk.u;
        }
}

// ---------------------------------------------------------------------------
extern "C" void kernel_launch(void* const* d_in, const int* in_sizes, int n_in,
                              void* d_out, int out_size, void* d_ws, size_t ws_size,
                              hipStream_t stream) {
    const float* x     = (const float*)d_in[0];
    const float* pos   = (const float*)d_in[1];
    const float* Wqkv  = (const float*)d_in[2];
    const float* bqkv  = (const float*)d_in[3];
    const float* loraA = (const float*)d_in[4];
    const float* loraB = (const float*)d_in[5];
    const float* Wproj = (const float*)d_in[6];
    const float* bproj = (const float*)d_in[7];
    const float* ln1g  = (const float*)d_in[8];
    const float* ln1b  = (const float*)d_in[9];
    const float* ln2g  = (const float*)d_in[10];
    const float* ln2b  = (const float*)d_in[11];
    const float* W1    = (const float*)d_in[12];
    const float* b1    = (const float*)d_in[13];
    const float* W2    = (const float*)d_in[14];
    const float* b2    = (const float*)d_in[15];

    char* ws = (char*)d_ws;
    float* x1     = (float*)(ws + 0);            // 16 MB
    bf16*  hbuf   = (bf16*) (ws + 16777216);     // 8 MB
    bf16*  gbuf   = (bf16*) (ws + 50331648);     // 32 MB
    float* afterA = (float*)(ws + 83886080);     // 128 KB
    bf16*  Qb     = (bf16*) (ws + 84017152);     // 8 MB
    bf16*  Kb     = (bf16*) (ws + 92405760);     // 8 MB
    bf16*  Vt     = (bf16*) (ws + 100794368);    // 8 MB
    bf16*  Obf    = (bf16*) (ws + 109182976);    // 8 MB
    bf16*  Wqkvb  = (bf16*) (ws + 117571584);    // 6 MB
    bf16*  Wprojb = (bf16*) (ws + 123863040);    // 2 MB
    bf16*  W1b    = (bf16*) (ws + 125960192);    // 8 MB
    bf16*  W2b    = (bf16*) (ws + 134348800);    // 8 MB (end ~142.7 MB)

    cvt_all<<<12288, 256, 0, stream>>>(Wqkv, Wproj, W1, W2, Wqkvb, Wprojb, W1b, W2b);

    // ln1 + fused lora_a (one kernel, -8 MB hbuf re-read)
    ln_kernel<true><<<4096, 256, 0, stream>>>(x, pos, ln1g, ln1b, x1, hbuf, loraA, afterA);

    // QKV fused: M=4096, N=3072, K=1024 -> 192 blocks (gx=12); writes Qb/Kb/Vt
    gemm_bk64<1><<<192, 512, 0, stream>>>(hbuf, Wqkvb, bqkv, nullptr,
                                          afterA, loraB, Qb, Kb, Vt,
                                          4096, 3072, 1024, 12);

    attn_fused<<<512, 256, 0, stream>>>(Qb, Kb, Vt, Obf);

    // proj: M=4096, N=1024, K=1024 -> 512 blocks (gx=16)
    gemm_n64<<<512, 256, 0, stream>>>(Obf, Wprojb, bproj, x1, x1, 4096, 1024, 1024, 16);

    ln_kernel<false><<<4096, 256, 0, stream>>>(x1, nullptr, ln2g, ln2b, nullptr, hbuf, nullptr, nullptr);

    // W1: M=4096, N=4096, K=1024 -> 256 blocks (gx=16)
    gemm_bk64<2><<<256, 512, 0, stream>>>(hbuf, W1b, b1, gbuf,
                                          nullptr, nullptr, nullptr, nullptr, nullptr,
                                          4096, 4096, 1024, 16);

    // W2: M=4096, N=1024, K=4096 -> 512 blocks (gx=16)
    gemm_n64<<<512, 256, 0, stream>>>(gbuf, W2b, b2, x1, (float*)d_out, 4096, 1024, 4096, 16);

    (void)in_sizes; (void)n_in; (void)out_size; (void)ws_size;
}

// Round 14
// 355.174 us; speedup vs baseline: 1.0477x; 1.0143x over previous
//
#include <hip/hip_runtime.h>
#include <hip/hip_bf16.h>
#include <math.h>

typedef __hip_bfloat16 bf16;
typedef __attribute__((ext_vector_type(4))) float f32x4;
typedef __attribute__((ext_vector_type(16))) float f32x16;
typedef __attribute__((ext_vector_type(8))) short s16x8;

__device__ __forceinline__ void async_cp16(void* lds, const void* g) {
    __builtin_amdgcn_global_load_lds((const __attribute__((address_space(1))) void*)g,
                                     (__attribute__((address_space(3))) void*)lds, 16, 0, 0);
}

// tanh-form GELU (max |diff| vs exact-erf gelu ~3e-3; threshold 0.154)
__device__ __forceinline__ float gelu_fast(float x) {
    float y = 1.5957691216f * (x + 0.044715f * x * x * x);
    float t = __expf(y);
    float th = 1.0f - 2.0f / (t + 1.0f);
    return 0.5f * x * (1.0f + th);
}

// ---------------------------------------------------------------------------
// fused f32 -> bf16 cast of all four weight matrices (one launch)
// ---------------------------------------------------------------------------
__global__ __launch_bounds__(256)
void cvt_all(const float* __restrict__ w0, const float* __restrict__ w1,
             const float* __restrict__ w2, const float* __restrict__ w3,
             bf16* __restrict__ o0, bf16* __restrict__ o1,
             bf16* __restrict__ o2, bf16* __restrict__ o3) {
    int i = blockIdx.x * 256 + threadIdx.x;
    const float* src; bf16* dst; int j = i;
    if (j < 786432)            { src = w0; dst = o0; }
    else if (j < 1048576)      { j -= 786432;  src = w1; dst = o1; }
    else if (j < 2097152)      { j -= 1048576; src = w2; dst = o2; }
    else                       { j -= 2097152; src = w3; dst = o3; }
    float4 v = ((const float4*)src)[j];
    union { bf16 o[4]; uint2 u; } pk;
    pk.o[0] = __float2bfloat16(v.x); pk.o[1] = __float2bfloat16(v.y);
    pk.o[2] = __float2bfloat16(v.z); pk.o[3] = __float2bfloat16(v.w);
    ((uint2*)dst)[j] = pk.u;
}

// ---------------------------------------------------------------------------
// LayerNorm. ADD variant: x1 = x + pos first, AND fused lora_a epilogue.
// ---------------------------------------------------------------------------
template <bool ADD>
__global__ __launch_bounds__(256)
void ln_kernel(const float* __restrict__ xin, const float* __restrict__ pos,
               const float* __restrict__ gam, const float* __restrict__ bet,
               float* __restrict__ x1, bf16* __restrict__ hout,
               const float* __restrict__ loraA, float* __restrict__ afterA) {
    const int row = blockIdx.x, tid = threadIdx.x;
    const size_t off = (size_t)row * 1024;
    float4 v = ((const float4*)(xin + off))[tid];
    if constexpr (ADD) {
        float4 p = ((const float4*)(pos + off))[tid];
        v.x += p.x; v.y += p.y; v.z += p.z; v.w += p.w;
        ((float4*)(x1 + off))[tid] = v;
    }
    float s  = v.x + v.y + v.z + v.w;
    float s2 = v.x*v.x + v.y*v.y + v.z*v.z + v.w*v.w;
#pragma unroll
    for (int o = 32; o >= 1; o >>= 1) { s += __shfl_xor(s, o); s2 += __shfl_xor(s2, o); }
    __shared__ float sS[4], sS2[4];
    int w = tid >> 6, lane = tid & 63;
    if (lane == 0) { sS[w] = s; sS2[w] = s2; }
    __syncthreads();
    float mean = (sS[0] + sS[1] + sS[2] + sS[3]) * (1.f / 1024.f);
    float e2   = (sS2[0] + sS2[1] + sS2[2] + sS2[3]) * (1.f / 1024.f);
    float rstd = rsqrtf(e2 - mean * mean + 1e-5f);
    float4 gv = ((const float4*)gam)[tid], bv = ((const float4*)bet)[tid];
    float h0 = (v.x - mean) * rstd * gv.x + bv.x;
    float h1 = (v.y - mean) * rstd * gv.y + bv.y;
    float h2 = (v.z - mean) * rstd * gv.z + bv.z;
    float h3 = (v.w - mean) * rstd * gv.w + bv.w;
    bf16* ho = hout + off + tid * 4;
    ho[0] = __float2bfloat16(h0);
    ho[1] = __float2bfloat16(h1);
    ho[2] = __float2bfloat16(h2);
    ho[3] = __float2bfloat16(h3);
    if constexpr (ADD) {
        float p[8];
#pragma unroll
        for (int r = 0; r < 8; r++) {
            float4 av = ((const float4*)(loraA + (size_t)r * 1024))[tid];
            p[r] = h0 * av.x + h1 * av.y + h2 * av.z + h3 * av.w;
        }
#pragma unroll
        for (int r = 0; r < 8; r++)
#pragma unroll
            for (int o = 32; o >= 1; o >>= 1) p[r] += __shfl_xor(p[r], o);
        __shared__ float red[4][8];
        if (lane == 0) {
#pragma unroll
            for (int r = 0; r < 8; r++) red[w][r] = p[r];
        }
        __syncthreads();
        if (tid < 8) afterA[(size_t)row * 8 + tid] = red[0][tid] + red[1][tid] + red[2][tid] + red[3][tid];
    }
}

// ---------------------------------------------------------------------------
// GEMM 256x256 tile, BK=64 — R9 skeleton (separate As[2]/Bs[2]).
// 512 threads, 8 waves 2M x 4N, wave tile 128x64 (acc[8][4]), double-
// buffered counted-vmcnt depth-1. LDS 128 KB -> 1 block/CU, 2 waves/SIMD.
// MODE 1 = fused QKV epilogue (Qb/Kb/Vt, Vt transposed via Bs 2-pass).
// MODE 2 = gelu(acc + bias) (W1).
// ---------------------------------------------------------------------------
template <int MODE>
__global__ __launch_bounds__(512, 2)
void gemm_bk64(const bf16* __restrict__ A, const bf16* __restrict__ B,
               const float* __restrict__ bias, bf16* __restrict__ outp,
               const float* __restrict__ afterA, const float* __restrict__ loraB,
               bf16* __restrict__ Qb, bf16* __restrict__ Kb, bf16* __restrict__ Vt,
               int M, int N, int K, int gx) {
    __shared__ bf16 As[2][256 * 64];
    __shared__ bf16 Bs[2][256 * 64];
    const int tid = threadIdx.x;
    const int lane = tid & 63, w = tid >> 6;
    const int grp = lane >> 4, c16 = lane & 15;
    const int wm = (w & 1) * 128, wn = (w >> 1) * 64;   // 8 waves: 2M x 4N
    const int nwg = gridDim.x, bid = blockIdx.x;
    const int sw = (bid & 7) * (nwg >> 3) + (bid >> 3);   // XCD chunk swizzle
    const int bm = (sw / gx) * 256, bn = (sw % gx) * 256;

    f32x4 acc[8][4];
    const f32x4 zero = {0.f, 0.f, 0.f, 0.f};
#pragma unroll
    for (int mi = 0; mi < 8; mi++)
#pragma unroll
        for (int ni = 0; ni < 4; ni++) acc[mi][ni] = zero;

#define STAGE256(bufi, k0)                                                          \
    {                                                                               \
        const int buf_ = (bufi);                                                    \
        const int koff_ = (k0);                                                     \
        _Pragma("unroll") for (int t_ = 0; t_ < 4; t_++) {                          \
            int s_ = t_ * 512 + tid;                                                \
            int row_ = s_ >> 3, db_ = s_ & 7;                                       \
            int gb_ = (db_ ^ (row_ & 7)) << 3;                                      \
            async_cp16(&As[buf_][s_ * 8], A + (size_t)(bm + row_) * K + koff_ + gb_); \
            async_cp16(&Bs[buf_][s_ * 8], B + (size_t)(bn + row_) * K + koff_ + gb_); \
        }                                                                           \
    }

#define COMPUTE256(bufi)                                                            \
    {                                                                               \
        const int buf_ = (bufi);                                                    \
        _Pragma("unroll") for (int kc_ = 0; kc_ < 2; kc_++) {                       \
            s16x8 af_[8], bfv_[4];                                                  \
            _Pragma("unroll") for (int mi_ = 0; mi_ < 8; mi_++) {                   \
                int r_ = wm + mi_ * 16 + c16;                                       \
                af_[mi_] = *(const s16x8*)&As[buf_][r_ * 64 + ((((kc_ << 2) | grp) ^ (r_ & 7)) << 3)]; \
            }                                                                       \
            _Pragma("unroll") for (int ni_ = 0; ni_ < 4; ni_++) {                   \
                int r_ = wn + ni_ * 16 + c16;                                       \
                bfv_[ni_] = *(const s16x8*)&Bs[buf_][r_ * 64 + ((((kc_ << 2) | grp) ^ (r_ & 7)) << 3)]; \
            }                                                                       \
            _Pragma("unroll") for (int mi_ = 0; mi_ < 8; mi_++)                     \
                _Pragma("unroll") for (int ni_ = 0; ni_ < 4; ni_++)                 \
                    acc[mi_][ni_] = __builtin_amdgcn_mfma_f32_16x16x32_bf16(af_[mi_], bfv_[ni_], acc[mi_][ni_], 0, 0, 0); \
        }                                                                           \
    }

#define WAITV8 asm volatile("s_waitcnt vmcnt(8)" ::: "memory")
#define WAITV0 asm volatile("s_waitcnt vmcnt(0)" ::: "memory")

#define STEP256(BQ, TQ)                                                             \
    {                                                                               \
        const int tq_ = (TQ);                                                       \
        COMPUTE256(BQ);                                                             \
        __builtin_amdgcn_s_barrier();        /* all waves done reading buf BQ */    \
        if (tq_ + 2 < nk) { STAGE256(BQ, (tq_ + 2) << 6); WAITV8; }                 \
        else { WAITV0; }                     /* tile TQ+1 now complete */           \
        __builtin_amdgcn_s_barrier();        /* everyone's TQ+1 loads landed */     \
    }

    const int nk = K >> 6;                   // K=1024 -> nk=16 (even)
    STAGE256(0, 0);
    STAGE256(1, 64);
    WAITV8;                                  // tile 0 complete
    __builtin_amdgcn_s_barrier();

    for (int t = 0; t < nk - 2; t += 2) {
        STEP256(0, t);
        STEP256(1, t + 1);
    }
    STEP256(0, nk - 2);                      // stages nothing; WAITV0
    COMPUTE256(1);                           // tile nk-1 in buf 1

#undef STEP256
#undef WAITV8
#undef WAITV0
#undef STAGE256
#undef COMPUTE256

    if constexpr (MODE == 1) {
        // fused QKV epilogue. role: 0=q, 1=k, 2=v (block-uniform).
        const int role = bn >> 10;
        const int g_b  = bm >> 11;           // batch index (rows 256-aligned)
        if (role == 2) {
            // v: bias + LoRA, transpose through Bs (64 KB window), 2 passes.
            char* tp = (char*)&Bs[0][0];     // 256 feat x 128 tok bf16, 256B rows
            const int tokb = bm & 2047;
#pragma unroll
            for (int pass = 0; pass < 2; pass++) {
                if ((wm >> 7) == pass) {     // this wave's tokens in this half
#pragma unroll
                    for (int mi = 0; mi < 8; mi++) {
                        float4 aA4[4];
#pragma unroll
                        for (int q = 0; q < 4; q++) {
                            int grow = bm + wm + mi * 16 + grp * 4 + q;
                            aA4[q] = ((const float4*)afterA)[(size_t)grow * 2 + 1];
                        }
#pragma unroll
                        for (int ni = 0; ni < 4; ni++) {
                            int fl = wn + ni * 16 + c16;      // feature 0..255
                            int cr = (bn & 1023) + fl;
                            float bv = bias[bn + fl];
                            float4 bw = ((const float4*)loraB)[1024 + cr];
                            union { bf16 e[4]; uint2 u; } pk;
#pragma unroll
                            for (int q = 0; q < 4; q++) {
                                float dv = (aA4[q].x*bw.x + aA4[q].y*bw.y + aA4[q].z*bw.z + aA4[q].w*bw.w) * 0.25f;
                                pk.e[q] = __float2bfloat16(acc[mi][ni][q] + bv + dv);
                            }
                            int tl = mi * 16 + grp * 4;       // 0..124 in half
                            int off = (fl * 256 + tl * 2) ^ ((fl & 7) << 3);
                            *(uint2*)(tp + off) = pk.u;
                        }
                    }
                }
                __syncthreads();
#pragma unroll
                for (int it = 0; it < 16; it++) {
                    int s = it * 512 + tid;
                    int fl = s >> 5, c4 = s & 31;             // 32 lanes = 1 feat
                    int off = (fl * 256 + c4 * 8) ^ ((fl & 7) << 3);
                    uint2 v = *(uint2*)(tp + off);
                    int cr = (bn & 1023) + fl;
                    int h = cr >> 6, d = cr & 63;
                    *(uint2*)&Vt[((size_t)(g_b * 16 + h) * 64 + d) * 2048 + tokb + pass * 128 + c4 * 4] = v;
                }
                if (pass == 0) __syncthreads();
            }
        } else if (role == 0) {
#pragma unroll
            for (int mi = 0; mi < 8; mi++) {
                float4 aA4[4];
#pragma unroll
                for (int q = 0; q < 4; q++) {
                    int grow = bm + wm + mi * 16 + grp * 4 + q;
                    aA4[q] = ((const float4*)afterA)[(size_t)grow * 2];
                }
#pragma unroll
                for (int ni = 0; ni < 4; ni++) {
                    int c  = bn + wn + ni * 16 + c16;
                    int cr = c & 1023;
                    int h  = cr >> 6, d = cr & 63;
                    float bv = bias[c];
                    float4 bw = ((const float4*)loraB)[cr];
#pragma unroll
                    for (int q = 0; q < 4; q++) {
                        int grow = bm + wm + mi * 16 + grp * 4 + q;
                        float dq = (aA4[q].x*bw.x + aA4[q].y*bw.y + aA4[q].z*bw.z + aA4[q].w*bw.w) * 0.25f;
                        float v = (acc[mi][ni][q] + bv + dq) * 0.18033688011f;  // 0.125*log2(e)
                        Qb[((size_t)(g_b * 16 + h) * 2048 + (grow & 2047)) * 64 + d] = __float2bfloat16(v);
                    }
                }
            }
        } else {
#pragma unroll
            for (int mi = 0; mi < 8; mi++)
#pragma unroll
                for (int ni = 0; ni < 4; ni++) {
                    int c  = bn + wn + ni * 16 + c16;
                    int cr = c & 1023;
                    int h  = cr >> 6, d = cr & 63;
                    float bv = bias[c];
#pragma unroll
                    for (int q = 0; q < 4; q++) {
                        int grow = bm + wm + mi * 16 + grp * 4 + q;
                        Kb[((size_t)(g_b * 16 + h) * 2048 + (grow & 2047)) * 64 + d] =
                            __float2bfloat16(acc[mi][ni][q] + bv);
                    }
                }
        }
    } else {
#pragma unroll
        for (int mi = 0; mi < 8; mi++)
#pragma unroll
            for (int ni = 0; ni < 4; ni++) {
                int r0 = bm + wm + mi * 16 + grp * 4;
                int c  = bn + wn + ni * 16 + c16;
                float bv = bias[c];
#pragma unroll
                for (int q = 0; q < 4; q++) {
                    size_t idx = (size_t)(r0 + q) * N + c;
                    float v = acc[mi][ni][q] + bv;
                    if constexpr (MODE == 2) v = gelu_fast(v);
                    outp[idx] = __float2bfloat16(v);
                }
            }
    }
}

// ---------------------------------------------------------------------------
// GEMM 128x64 tile, BK=64 — R7 config (proven), used for proj only now.
// TRIPLE-BUFFERED counted-vmcnt. REQUIRES (K/64 - 1) % 3 == 0.
// Epilogue: out fp32 = acc + bias + resid.  1-D grid + XCD swizzle; gx=N/64.
// ---------------------------------------------------------------------------
__global__ __launch_bounds__(256)
void gemm_n64(const bf16* __restrict__ A, const bf16* __restrict__ B,
              const float* __restrict__ bias, const float* __restrict__ resid,
              float* __restrict__ outp, int M, int N, int K, int gx) {
    __shared__ bf16 As[3][128 * 64];
    __shared__ bf16 Bs[3][64 * 64];
    const int tid = threadIdx.x;
    const int lane = tid & 63, w = tid >> 6;
    const int grp = lane >> 4, c16 = lane & 15;
    const int wm = w * 32;
    const int nwg = gridDim.x, bid = blockIdx.x;
    const int sw = (bid & 7) * (nwg >> 3) + (bid >> 3);
    const int bm = (sw / gx) * 128, bn = (sw % gx) * 64;

    f32x4 acc[2][4];
    const f32x4 zero = {0.f, 0.f, 0.f, 0.f};
#pragma unroll
    for (int mi = 0; mi < 2; mi++)
#pragma unroll
        for (int ni = 0; ni < 4; ni++) acc[mi][ni] = zero;

#define STAGE64(bufi, k0)                                                           \
    {                                                                               \
        const int buf_ = (bufi);                                                    \
        const int koff_ = (k0);                                                     \
        _Pragma("unroll") for (int t_ = 0; t_ < 4; t_++) {                          \
            int s_ = t_ * 256 + tid;                                                \
            int row_ = s_ >> 3, db_ = s_ & 7;                                       \
            async_cp16(&As[buf_][s_ * 8], A + (size_t)(bm + row_) * K + koff_ + ((db_ ^ (row_ & 7)) << 3)); \
        }                                                                           \
        _Pragma("unroll") for (int t_ = 0; t_ < 2; t_++) {                          \
            int s_ = t_ * 256 + tid;                                                \
            int row_ = s_ >> 3, db_ = s_ & 7;                                       \
            async_cp16(&Bs[buf_][s_ * 8], B + (size_t)(bn + row_) * K + koff_ + ((db_ ^ (row_ & 7)) << 3)); \
        }                                                                           \
    }

#define COMPUTE64(bufi)                                                             \
    {                                                                               \
        const int buf_ = (bufi);                                                    \
        _Pragma("unroll") for (int kc_ = 0; kc_ < 2; kc_++) {                       \
            s16x8 af_[2], bfv_[4];                                                  \
            _Pragma("unroll") for (int mi_ = 0; mi_ < 2; mi_++) {                   \
                int r_ = wm + mi_ * 16 + c16;                                       \
                af_[mi_] = *(const s16x8*)&As[buf_][r_ * 64 + ((((kc_ << 2) | grp) ^ (r_ & 7)) << 3)]; \
            }                                                                       \
            _Pragma("unroll") for (int ni_ = 0; ni_ < 4; ni_++) {                   \
                int rb_ = ni_ * 16 + c16;                                           \
                bfv_[ni_] = *(const s16x8*)&Bs[buf_][rb_ * 64 + ((((kc_ << 2) | grp) ^ (rb_ & 7)) << 3)]; \
            }                                                                       \
            _Pragma("unroll") for (int mi_ = 0; mi_ < 2; mi_++)                     \
                _Pragma("unroll") for (int ni_ = 0; ni_ < 4; ni_++)                 \
                    acc[mi_][ni_] = __builtin_amdgcn_mfma_f32_16x16x32_bf16(af_[mi_], bfv_[ni_], acc[mi_][ni_], 0, 0, 0); \
        }                                                                           \
    }

#define WAITV12 asm volatile("s_waitcnt vmcnt(12)" ::: "memory")
#define WAITV6  asm volatile("s_waitcnt vmcnt(6)"  ::: "memory")
#define WAITV0  asm volatile("s_waitcnt vmcnt(0)"  ::: "memory")

#define STEP64(BQ, TQ)                                                              \
    {                                                                               \
        const int tq_ = (TQ);                                                       \
        COMPUTE64(BQ);                                                              \
        __builtin_amdgcn_s_barrier();        /* all waves done reading buf BQ */    \
        if (tq_ + 3 < nk) { STAGE64(BQ, (tq_ + 3) << 6); WAITV12; }                 \
        else if (tq_ + 2 < nk) { WAITV6; }                                          \
        else { WAITV0; }                     /* tile TQ+1 now complete */           \
        __builtin_amdgcn_s_barrier();        /* everyone's TQ+1 loads landed */     \
    }

    const int nk = K >> 6;
    STAGE64(0, 0);
    STAGE64(1, 64);
    STAGE64(2, 128);
    WAITV12;                                 // tile 0 complete
    __builtin_amdgcn_s_barrier();

    for (int t = 0; t < nk - 1; t += 3) {    // nk-1 divisible by 3
        STEP64(0, t);
        STEP64(1, t + 1);
        STEP64(2, t + 2);
    }
    COMPUTE64(0);                            // tile nk-1, (nk-1)%3 == 0

#undef STEP64
#undef WAITV12
#undef WAITV6
#undef WAITV0
#undef STAGE64
#undef COMPUTE64

#pragma unroll
    for (int mi = 0; mi < 2; mi++)
#pragma unroll
        for (int ni = 0; ni < 4; ni++) {
            int r0 = bm + wm + mi * 16 + grp * 4;
            int c  = bn + ni * 16 + c16;
            float bv = bias[c];
#pragma unroll
            for (int q = 0; q < 4; q++) {
                size_t idx = (size_t)(r0 + q) * N + c;
                outp[idx] = acc[mi][ni][q] + bv + resid[idx];
            }
        }
}

// ---------------------------------------------------------------------------
// GEMM W2 SPLIT-K=2 (R14): 128x128 tile, 256 threads, 4 waves of 64x64
// (acc[4][4] -> 0.5 LDS-reads/MFMA vs gemm_n64's 0.75 — W2 measured AT the
// LDS-BW ceiling). Split-K doubles the grid to 512 blocks so the 0.5-ratio
// shape still fills all CUs at 2 blocks/CU (2 waves/SIMD; the 0.5-shape
// without split gives only 256 blocks = 1 wave/SIMD = R8 failure).
// Each block: 128x128 over K/2 (nk=32, even) with the R9-verified 2-buf
// depth-1 counted-vmcnt ladder 8/0. LDS 2 x 32 KB = 64 KB.
// ks=0 writes out = acc + bias + resid (f32); ks=1 writes raw f32 partial;
// add_part combines.  1-D grid + XCD swizzle (512 % 8 == 0).
// ---------------------------------------------------------------------------
__global__ __launch_bounds__(256)
void gemm_w2sk(const bf16* __restrict__ A, const bf16* __restrict__ B,
               const float* __restrict__ bias, const float* __restrict__ resid,
               float* __restrict__ outp, float* __restrict__ part1,
               int M, int N, int K, int gx) {
    __shared__ bf16 As[2][128 * 64];
    __shared__ bf16 Bs[2][128 * 64];
    const int tid = threadIdx.x;
    const int lane = tid & 63, w = tid >> 6;
    const int grp = lane >> 4, c16 = lane & 15;
    const int wm = (w & 1) * 64, wn = (w >> 1) * 64;   // 4 waves: 2M x 2N
    const int nwg = gridDim.x, bid = blockIdx.x;
    const int sw = (bid & 7) * (nwg >> 3) + (bid >> 3);
    const int ks = sw >> 8;                  // 0..511 -> K-split half
    const int id2 = sw & 255;
    const int bm = (id2 / gx) * 128, bn = (id2 % gx) * 128;
    const int kbase = ks * (K >> 1);

    f32x4 acc[4][4];
    const f32x4 zero = {0.f, 0.f, 0.f, 0.f};
#pragma unroll
    for (int mi = 0; mi < 4; mi++)
#pragma unroll
        for (int ni = 0; ni < 4; ni++) acc[mi][ni] = zero;

#define STAGEW2(bufi, k0)                                                           \
    {                                                                               \
        const int buf_ = (bufi);                                                    \
        const int koff_ = kbase + (k0);                                             \
        _Pragma("unroll") for (int t_ = 0; t_ < 4; t_++) {                          \
            int s_ = t_ * 256 + tid;                                                \
            int row_ = s_ >> 3, db_ = s_ & 7;                                       \
            int gb_ = (db_ ^ (row_ & 7)) << 3;                                      \
            async_cp16(&As[buf_][s_ * 8], A + (size_t)(bm + row_) * K + koff_ + gb_); \
            async_cp16(&Bs[buf_][s_ * 8], B + (size_t)(bn + row_) * K + koff_ + gb_); \
        }                                                                           \
    }

#define COMPUTEW2(bufi)                                                             \
    {                                                                               \
        const int buf_ = (bufi);                                                    \
        _Pragma("unroll") for (int kc_ = 0; kc_ < 2; kc_++) {                       \
            s16x8 af_[4], bfv_[4];                                                  \
            _Pragma("unroll") for (int mi_ = 0; mi_ < 4; mi_++) {                   \
                int r_ = wm + mi_ * 16 + c16;                                       \
                af_[mi_] = *(const s16x8*)&As[buf_][r_ * 64 + ((((kc_ << 2) | grp) ^ (r_ & 7)) << 3)]; \
            }                                                                       \
            _Pragma("unroll") for (int ni_ = 0; ni_ < 4; ni_++) {                   \
                int r_ = wn + ni_ * 16 + c16;                                       \
                bfv_[ni_] = *(const s16x8*)&Bs[buf_][r_ * 64 + ((((kc_ << 2) | grp) ^ (r_ & 7)) << 3)]; \
            }                                                                       \
            _Pragma("unroll") for (int mi_ = 0; mi_ < 4; mi_++)                     \
                _Pragma("unroll") for (int ni_ = 0; ni_ < 4; ni_++)                 \
                    acc[mi_][ni_] = __builtin_amdgcn_mfma_f32_16x16x32_bf16(af_[mi_], bfv_[ni_], acc[mi_][ni_], 0, 0, 0); \
        }                                                                           \
    }

#define WAITV8 asm volatile("s_waitcnt vmcnt(8)" ::: "memory")
#define WAITV0 asm volatile("s_waitcnt vmcnt(0)" ::: "memory")

#define STEPW2(BQ, TQ)                                                              \
    {                                                                               \
        const int tq_ = (TQ);                                                       \
        COMPUTEW2(BQ);                                                              \
        __builtin_amdgcn_s_barrier();                                               \
        if (tq_ + 2 < nk) { STAGEW2(BQ, (tq_ + 2) << 6); WAITV8; }                  \
        else { WAITV0; }                                                            \
        __builtin_amdgcn_s_barrier();                                               \
    }

    const int nk = K >> 7;                   // half-K in BK=64 steps: 4096 -> 32
    STAGEW2(0, 0);
    STAGEW2(1, 64);
    WAITV8;
    __builtin_amdgcn_s_barrier();

    for (int t = 0; t < nk - 2; t += 2) {
        STEPW2(0, t);
        STEPW2(1, t + 1);
    }
    STEPW2(0, nk - 2);                       // stages nothing; WAITV0
    COMPUTEW2(1);                            // tile nk-1 in buf 1

#undef STEPW2
#undef WAITV8
#undef WAITV0
#undef STAGEW2
#undef COMPUTEW2

#pragma unroll
    for (int mi = 0; mi < 4; mi++)
#pragma unroll
        for (int ni = 0; ni < 4; ni++) {
            int r0 = bm + wm + mi * 16 + grp * 4;
            int c  = bn + wn + ni * 16 + c16;
            if (ks == 0) {
                float bv = bias[c];
#pragma unroll
                for (int q = 0; q < 4; q++) {
                    size_t idx = (size_t)(r0 + q) * N + c;
                    outp[idx] = acc[mi][ni][q] + bv + resid[idx];
                }
            } else {
#pragma unroll
                for (int q = 0; q < 4; q++) {
                    size_t idx = (size_t)(r0 + q) * N + c;
                    part1[idx] = acc[mi][ni][q];
                }
            }
        }
}

// ---------------------------------------------------------------------------
// split-K combine: out += part1 (float4 vectorized)
// ---------------------------------------------------------------------------
__global__ __launch_bounds__(256)
void add_part(float* __restrict__ outp, const float* __restrict__ p1) {
    int i = blockIdx.x * 256 + threadIdx.x;
    float4 a = ((float4*)outp)[i];
    float4 b = ((const float4*)p1)[i];
    a.x += b.x; a.y += b.y; a.z += b.z; a.w += b.w;
    ((float4*)outp)[i] = a;
}

// ---------------------------------------------------------------------------
// Flash attention, S-transposed, mfma_32x32x16, static-shift softmax.
// ---------------------------------------------------------------------------
__global__ __launch_bounds__(256)
void attn_fused(const bf16* __restrict__ Qb, const bf16* __restrict__ Kb,
                const bf16* __restrict__ Vt, bf16* __restrict__ Og) {
    __shared__ bf16 Qs[128 * 64], Ks[2][64 * 64], Vs[2][64 * 64];
    const int tid = threadIdx.x;
    const int lane = tid & 63, w = tid >> 6;
    const int c32 = lane & 31, l5 = lane >> 5;
    const int bid = blockIdx.x;
    const int sw = (bid & 7) * 64 + (bid >> 3);   // XCD grouping (512 blocks)
    const int bh = sw >> 4, b = bh >> 4, h = bh & 15;
    const int i0 = (sw & 15) * 128;
    const int rowperm = (c32 & 19) | (((c32 >> 3) & 1) << 2) | (((c32 >> 2) & 1) << 3);

    const size_t qbase = (size_t)(bh * 2048 + i0) * 64;
    const size_t kbase = (size_t)bh * 2048 * 64;
    const size_t vbase = (size_t)bh * 64 * 2048;

#define STAGEKV(bufi, jv)                                                           \
    {                                                                               \
        const int buf_ = (bufi);                                                    \
        const int joff_ = (jv);                                                     \
        _Pragma("unroll") for (int t_ = 0; t_ < 2; t_++) {                          \
            int s_ = t_ * 256 + tid;                                                \
            int row_ = s_ >> 3, db_ = s_ & 7;                                       \
            int gb_ = (db_ ^ (row_ & 7)) << 3;                                      \
            async_cp16(&Ks[buf_][s_ * 8], Kb + kbase + (size_t)(joff_ + row_) * 64 + gb_); \
            async_cp16(&Vs[buf_][s_ * 8], Vt + vbase + (size_t)row_ * 2048 + joff_ + gb_); \
        }                                                                           \
    }

    // prologue: Q tile + first K/V tile in one stage, one barrier
#pragma unroll
    for (int t = 0; t < 4; t++) {
        int s = t * 256 + tid;
        int row = s >> 3, db = s & 7;
        async_cp16(&Qs[s * 8], Qb + qbase + row * 64 + ((db ^ (row & 7)) << 3));
    }
    STAGEKV(0, 0);
    __syncthreads();

    s16x8 qf[4];
    {
        int rq = w * 32 + c32;
#pragma unroll
        for (int kc = 0; kc < 4; kc++) {
            int db = 2 * kc + l5;
            qf[kc] = *(const s16x8*)&Qs[rq * 64 + ((db ^ (rq & 7)) << 3)];
        }
    }

    f32x16 Oq[2];
#pragma unroll
    for (int dq = 0; dq < 2; dq++)
#pragma unroll
        for (int r = 0; r < 16; r++) Oq[dq][r] = 0.f;
    float l_lane = 0.f;

#define ATILE(BUF, JN)                                                              \
    {                                                                               \
        const int jn_ = (JN);                                                       \
        if (jn_ < 32) { STAGEKV((BUF) ^ 1, jn_ << 6); }                             \
        f32x16 Sq[2];                                                               \
        __builtin_amdgcn_s_setprio(1);                                              \
        _Pragma("unroll") for (int jq_ = 0; jq_ < 2; jq_++) {                       \
            _Pragma("unroll") for (int r_ = 0; r_ < 16; r_++) Sq[jq_][r_] = 0.f;    \
            int rk_ = jq_ * 32 + rowperm;                                           \
            _Pragma("unroll") for (int kc_ = 0; kc_ < 4; kc_++) {                   \
                int db_ = 2 * kc_ + l5;                                             \
                s16x8 af_ = *(const s16x8*)&Ks[BUF][rk_ * 64 + ((db_ ^ (rk_ & 7)) << 3)]; \
                Sq[jq_] = __builtin_amdgcn_mfma_f32_32x32x16_bf16(af_, qf[kc_], Sq[jq_], 0, 0, 0); \
            }                                                                       \
        }                                                                           \
        __builtin_amdgcn_s_setprio(0);                                              \
        s16x8 pf_[4];                                                               \
        _Pragma("unroll") for (int kc_ = 0; kc_ < 4; kc_++) {                       \
            union { s16x8 v; unsigned u4[4]; } u_;                                  \
            _Pragma("unroll") for (int pr_ = 0; pr_ < 4; pr_++) {                   \
                float a_ = Sq[kc_ >> 1][8 * (kc_ & 1) + 2 * pr_];                   \
                float b_ = Sq[kc_ >> 1][8 * (kc_ & 1) + 2 * pr_ + 1];               \
                float pa_, pb_;                                                     \
                asm("v_exp_f32 %0, %1" : "=v"(pa_) : "v"(a_));                      \
                asm("v_exp_f32 %0, %1" : "=v"(pb_) : "v"(b_));                      \
                l_lane += pa_; l_lane += pb_;                                       \
                unsigned pk_;                                                       \
                asm("v_cvt_pk_bf16_f32 %0, %1, %2" : "=v"(pk_) : "v"(pa_), "v"(pb_)); \
                u_.u4[pr_] = pk_;                                                   \
            }                                                                       \
            pf_[kc_] = u_.v;                                                        \
        }                                                                           \
        __builtin_amdgcn_s_setprio(1);                                              \
        _Pragma("unroll") for (int dq_ = 0; dq_ < 2; dq_++) {                       \
            int rd_ = dq_ * 32 + c32;                                               \
            _Pragma("unroll") for (int kc_ = 0; kc_ < 4; kc_++) {                   \
                int jb_ = 2 * kc_ + l5;                                             \
                s16x8 af_ = *(const s16x8*)&Vs[BUF][rd_ * 64 + ((jb_ ^ (rd_ & 7)) << 3)]; \
                Oq[dq_] = __builtin_amdgcn_mfma_f32_32x32x16_bf16(af_, pf_[kc_], Oq[dq_], 0, 0, 0); \
            }                                                                       \
        }                                                                           \
        __builtin_amdgcn_s_setprio(0);                                              \
        __syncthreads();                                                            \
    }

    for (int jt = 0; jt < 32; jt += 2) {
        ATILE(0, jt + 1);
        ATILE(1, jt + 2);
    }
#undef ATILE
#undef STAGEKV

    float l = l_lane + __shfl_xor(l_lane, 32);
    float inv = 1.0f / fmaxf(l, 1e-35f);
    int i = i0 + w * 32 + c32;
    size_t obase = (size_t)(b * 2048 + i) * 1024 + h * 64;
#pragma unroll
    for (int dq = 0; dq < 2; dq++)
#pragma unroll
        for (int rg = 0; rg < 4; rg++) {
            union { bf16 e[4]; uint2 u; } pk;
#pragma unroll
            for (int c = 0; c < 4; c++)
                pk.e[c] = __float2bfloat16(Oq[dq][rg * 4 + c] * inv);
            int d0 = dq * 32 + l5 * 4 + rg * 8;
            *(uint2*)&Og[obase + d0] = pk.u;
        }
}

// ---------------------------------------------------------------------------
extern "C" void kernel_launch(void* const* d_in, const int* in_sizes, int n_in,
                              void* d_out, int out_size, void* d_ws, size_t ws_size,
                              hipStream_t stream) {
    const float* x     = (const float*)d_in[0];
    const float* pos   = (const float*)d_in[1];
    const float* Wqkv  = (const float*)d_in[2];
    const float* bqkv  = (const float*)d_in[3];
    const float* loraA = (const float*)d_in[4];
    const float* loraB = (const float*)d_in[5];
    const float* Wproj = (const float*)d_in[6];
    const float* bproj = (const float*)d_in[7];
    const float* ln1g  = (const float*)d_in[8];
    const float* ln1b  = (const float*)d_in[9];
    const float* ln2g  = (const float*)d_in[10];
    const float* ln2b  = (const float*)d_in[11];
    const float* W1    = (const float*)d_in[12];
    const float* b1    = (const float*)d_in[13];
    const float* W2    = (const float*)d_in[14];
    const float* b2    = (const float*)d_in[15];

    char* ws = (char*)d_ws;
    float* x1     = (float*)(ws + 0);            // 16 MB
    bf16*  hbuf   = (bf16*) (ws + 16777216);     // 8 MB
    float* part1  = (float*)(ws + 25165824);     // 16 MB (split-K partial)
    bf16*  gbuf   = (bf16*) (ws + 50331648);     // 32 MB
    float* afterA = (float*)(ws + 83886080);     // 128 KB
    bf16*  Qb     = (bf16*) (ws + 84017152);     // 8 MB
    bf16*  Kb     = (bf16*) (ws + 92405760);     // 8 MB
    bf16*  Vt     = (bf16*) (ws + 100794368);    // 8 MB
    bf16*  Obf    = (bf16*) (ws + 109182976);    // 8 MB
    bf16*  Wqkvb  = (bf16*) (ws + 117571584);    // 6 MB
    bf16*  Wprojb = (bf16*) (ws + 123863040);    // 2 MB
    bf16*  W1b    = (bf16*) (ws + 125960192);    // 8 MB
    bf16*  W2b    = (bf16*) (ws + 134348800);    // 8 MB (end ~142.7 MB)

    cvt_all<<<12288, 256, 0, stream>>>(Wqkv, Wproj, W1, W2, Wqkvb, Wprojb, W1b, W2b);

    // ln1 + fused lora_a
    ln_kernel<true><<<4096, 256, 0, stream>>>(x, pos, ln1g, ln1b, x1, hbuf, loraA, afterA);

    // QKV fused: M=4096, N=3072, K=1024 -> 192 blocks (gx=12); writes Qb/Kb/Vt
    gemm_bk64<1><<<192, 512, 0, stream>>>(hbuf, Wqkvb, bqkv, nullptr,
                                          afterA, loraB, Qb, Kb, Vt,
                                          4096, 3072, 1024, 12);

    attn_fused<<<512, 256, 0, stream>>>(Qb, Kb, Vt, Obf);

    // proj: M=4096, N=1024, K=1024 -> 512 blocks (gx=16)
    gemm_n64<<<512, 256, 0, stream>>>(Obf, Wprojb, bproj, x1, x1, 4096, 1024, 1024, 16);

    ln_kernel<false><<<4096, 256, 0, stream>>>(x1, nullptr, ln2g, ln2b, nullptr, hbuf, nullptr, nullptr);

    // W1: M=4096, N=4096, K=1024 -> 256 blocks (gx=16)
    gemm_bk64<2><<<256, 512, 0, stream>>>(hbuf, W1b, b1, gbuf,
                                          nullptr, nullptr, nullptr, nullptr, nullptr,
                                          4096, 4096, 1024, 16);

    // W2 split-K=2: M=4096, N=1024, K=4096 -> 512 blocks (gx=8)
    gemm_w2sk<<<512, 256, 0, stream>>>(gbuf, W2b, b2, x1, (float*)d_out, part1,
                                       4096, 1024, 4096, 8);
    // combine: out += part1 (4096*1024 floats / 4 / 256 = 4096 blocks)
    add_part<<<4096, 256, 0, stream>>>((float*)d_out, part1);

    (void)in_sizes; (void)n_in; (void)out_size; (void)ws_size;
}